// Round 2
// baseline (4433.361 us; speedup 1.0000x reference)
//
#include <hip/hip_runtime.h>
#include <math.h>

#define DD 128   // node / hidden dim
#define FF 64    // edge feature dim

__device__ __forceinline__ float ssp_f(float x) {
    // softplus(x) - ln(2), numerically stable
    float ax = fabsf(x);
    float e  = __expf(-ax);
    return fmaxf(x, 0.0f) + __logf(1.0f + e) - 0.6931471805599453f;
}

__global__ void copy_nodes_kernel(const float4* __restrict__ src,
                                  float4* __restrict__ dst, int n4) {
    int i = blockIdx.x * blockDim.x + threadIdx.x;
    int stride = gridDim.x * blockDim.x;
    for (; i < n4; i += stride) dst[i] = src[i];
}

__global__ void zero_u32_kernel(unsigned* __restrict__ p, int n) {
    int i = blockIdx.x * blockDim.x + threadIdx.x;
    int stride = gridDim.x * blockDim.x;
    for (; i < n; i += stride) p[i] = 0u;
}

__global__ void hist_kernel(const int* __restrict__ eidx,
                            unsigned* __restrict__ counts, int E) {
    int e = blockIdx.x * blockDim.x + threadIdx.x;
    if (e < E) atomicAdd(&counts[eidx[2 * e]], 1u);
}

// block-level exclusive scan (256/block) -> cursor, block totals -> bsums
__global__ void scan1_kernel(const unsigned* __restrict__ counts,
                             unsigned* __restrict__ cursor,
                             unsigned* __restrict__ bsums, int n) {
    __shared__ unsigned s[256];
    int i = blockIdx.x * 256 + threadIdx.x;
    unsigned v = (i < n) ? counts[i] : 0u;
    s[threadIdx.x] = v;
    __syncthreads();
    #pragma unroll
    for (int d = 1; d < 256; d <<= 1) {
        unsigned t = (threadIdx.x >= d) ? s[threadIdx.x - d] : 0u;
        __syncthreads();
        s[threadIdx.x] += t;
        __syncthreads();
    }
    if (i < n) cursor[i] = s[threadIdx.x] - v;   // exclusive
    if (threadIdx.x == 255) bsums[blockIdx.x] = s[255];
}

// serial scan of ~391 block sums (trivial)
__global__ void scan2_kernel(unsigned* __restrict__ bsums, int nb) {
    if (threadIdx.x == 0 && blockIdx.x == 0) {
        unsigned run = 0u;
        for (int i = 0; i < nb; ++i) {
            unsigned t = bsums[i];
            bsums[i] = run;
            run += t;
        }
    }
}

__global__ void scan3_kernel(unsigned* __restrict__ cursor,
                             const unsigned* __restrict__ bsums, int n) {
    int i = blockIdx.x * 256 + threadIdx.x;
    if (i < n) cursor[i] += bsums[blockIdx.x];
}

__global__ void scatter_ids_kernel(const int* __restrict__ eidx,
                                   unsigned* __restrict__ cursor,
                                   unsigned* __restrict__ sorted, int E) {
    int e = blockIdx.x * blockDim.x + threadIdx.x;
    if (e < E) {
        unsigned pos = atomicAdd(&cursor[eidx[2 * e]], 1u);
        sorted[pos] = (unsigned)e;
    }
}

__launch_bounds__(256, 2)
__global__ void edge_fused_kernel(const float* __restrict__ nodes,
                                  const float* __restrict__ edges,
                                  const int*   __restrict__ eidx,
                                  const float* __restrict__ W1,
                                  const float* __restrict__ b1,
                                  const float* __restrict__ W2,
                                  const float* __restrict__ b2,
                                  float* __restrict__ out,
                                  const unsigned* __restrict__ sorted,
                                  int E) {
    int i = blockIdx.x * 256 + threadIdx.x;
    if (i >= E) return;
    int e = sorted ? (int)sorted[i] : i;

    int ns = eidx[2 * e + 0];   // scatter target (starts)
    int nt = eidx[2 * e + 1];   // gather source (ends)

    // ---- GEMM1: h1 = ssp(edges[e] @ W1 + b1), h1 in 128 VGPRs ----
    float h1[DD];
    #pragma unroll
    for (int d = 0; d < DD; ++d) h1[d] = b1[d];

    const float4* ev4 = reinterpret_cast<const float4*>(edges) + (size_t)e * (FF / 4);
    #pragma unroll 1
    for (int f4 = 0; f4 < FF / 4; ++f4) {
        float4 ev = ev4[f4];
        const float* w0 = W1 + (size_t)(f4 * 4) * DD;
        #pragma unroll
        for (int d = 0; d < DD; ++d) h1[d] = fmaf(ev.x, w0[d], h1[d]);
        #pragma unroll
        for (int d = 0; d < DD; ++d) h1[d] = fmaf(ev.y, w0[DD + d], h1[d]);
        #pragma unroll
        for (int d = 0; d < DD; ++d) h1[d] = fmaf(ev.z, w0[2 * DD + d], h1[d]);
        #pragma unroll
        for (int d = 0; d < DD; ++d) h1[d] = fmaf(ev.w, w0[3 * DD + d], h1[d]);
    }

    #pragma unroll
    for (int d = 0; d < DD; ++d) h1[d] = ssp_f(h1[d]);

    const float* nrow = nodes + (size_t)nt * DD;
    float*       orow = out   + (size_t)ns * DD;

    // ---- GEMM2 in two 64-wide output chunks to bound VGPR pressure ----
    #pragma unroll 1
    for (int c = 0; c < 2; ++c) {
        const int base = c * 64;
        float h2[64];
        #pragma unroll
        for (int j = 0; j < 64; ++j) h2[j] = b2[base + j];

        #pragma unroll
        for (int k = 0; k < DD; ++k) {           // fully unrolled: h1[k] stays in regs
            float hk = h1[k];
            const float* w = W2 + (size_t)k * DD + base;
            #pragma unroll
            for (int j = 0; j < 64; ++j) h2[j] = fmaf(hk, w[j], h2[j]);
        }

        #pragma unroll
        for (int j = 0; j < 64; ++j) {
            float m = ssp_f(h2[j]) * nrow[base + j];
            __hip_atomic_fetch_add(&orow[base + j], m,
                                   __ATOMIC_RELAXED, __HIP_MEMORY_SCOPE_AGENT);
        }
    }
}

extern "C" void kernel_launch(void* const* d_in, const int* in_sizes, int n_in,
                              void* d_out, int out_size, void* d_ws, size_t ws_size,
                              hipStream_t stream) {
    const float* nodes = (const float*)d_in[0];
    const float* edges = (const float*)d_in[1];
    const int*   eidx  = (const int*)  d_in[2];
    const float* W1    = (const float*)d_in[3];
    const float* b1    = (const float*)d_in[4];
    const float* W2    = (const float*)d_in[5];
    const float* b2    = (const float*)d_in[6];
    float* out = (float*)d_out;

    int ND = in_sizes[0];        // N*D
    int N  = ND / DD;            // 100000
    int E  = in_sizes[1] / FF;   // 600000

    // out = nodes (copy), then scatter-add messages
    int n4 = ND / 4;
    copy_nodes_kernel<<<dim3(1024), dim3(256), 0, stream>>>(
        (const float4*)nodes, (float4*)out, n4);

    // ---- counting sort of edge ids by start node (locality for atomics) ----
    int nb = (N + 255) / 256;
    size_t need = ((size_t)2 * N + nb + E) * sizeof(unsigned);
    const unsigned* sorted_ptr = nullptr;

    if (ws_size >= need) {
        unsigned* counts = (unsigned*)d_ws;
        unsigned* cursor = counts + N;
        unsigned* bsums  = cursor + N;
        unsigned* sorted = bsums + nb;

        zero_u32_kernel<<<dim3(256), dim3(256), 0, stream>>>(counts, N);
        hist_kernel<<<dim3((E + 255) / 256), dim3(256), 0, stream>>>(eidx, counts, E);
        scan1_kernel<<<dim3(nb), dim3(256), 0, stream>>>(counts, cursor, bsums, N);
        scan2_kernel<<<dim3(1), dim3(64), 0, stream>>>(bsums, nb);
        scan3_kernel<<<dim3(nb), dim3(256), 0, stream>>>(cursor, bsums, N);
        scatter_ids_kernel<<<dim3((E + 255) / 256), dim3(256), 0, stream>>>(eidx, cursor, sorted, E);
        sorted_ptr = sorted;
    }

    edge_fused_kernel<<<dim3((E + 255) / 256), dim3(256), 0, stream>>>(
        nodes, edges, eidx, W1, b1, W2, b2, out, sorted_ptr, E);
}

// Round 3
// 1929.998 us; speedup vs baseline: 2.2971x; 2.2971x over previous
//
#include <hip/hip_runtime.h>
#include <math.h>

#define DD 128   // node / hidden dim
#define FF 64    // edge feature dim

__device__ __forceinline__ float ssp_f(float x) {
    // softplus(x) - ln(2), numerically stable
    float ax = fabsf(x);
    float e  = __expf(-ax);
    return fmaxf(x, 0.0f) + __logf(1.0f + e) - 0.6931471805599453f;
}

__global__ void copy_nodes_kernel(const float4* __restrict__ src,
                                  float4* __restrict__ dst, int n4) {
    int i = blockIdx.x * blockDim.x + threadIdx.x;
    int stride = gridDim.x * blockDim.x;
    for (; i < n4; i += stride) dst[i] = src[i];
}

__global__ void zero_u32_kernel(unsigned* __restrict__ p, int n) {
    int i = blockIdx.x * blockDim.x + threadIdx.x;
    int stride = gridDim.x * blockDim.x;
    for (; i < n; i += stride) p[i] = 0u;
}

__global__ void hist_kernel(const int* __restrict__ eidx,
                            unsigned* __restrict__ counts, int E) {
    int e = blockIdx.x * blockDim.x + threadIdx.x;
    if (e < E) atomicAdd(&counts[eidx[2 * e]], 1u);
}

// block-level exclusive scan (256/block) -> cursor, block totals -> bsums
__global__ void scan1_kernel(const unsigned* __restrict__ counts,
                             unsigned* __restrict__ cursor,
                             unsigned* __restrict__ bsums, int n) {
    __shared__ unsigned s[256];
    int i = blockIdx.x * 256 + threadIdx.x;
    unsigned v = (i < n) ? counts[i] : 0u;
    s[threadIdx.x] = v;
    __syncthreads();
    #pragma unroll
    for (int d = 1; d < 256; d <<= 1) {
        unsigned t = (threadIdx.x >= d) ? s[threadIdx.x - d] : 0u;
        __syncthreads();
        s[threadIdx.x] += t;
        __syncthreads();
    }
    if (i < n) cursor[i] = s[threadIdx.x] - v;   // exclusive
    if (threadIdx.x == 255) bsums[blockIdx.x] = s[255];
}

__global__ void scan2_kernel(unsigned* __restrict__ bsums, int nb) {
    if (threadIdx.x == 0 && blockIdx.x == 0) {
        unsigned run = 0u;
        for (int i = 0; i < nb; ++i) {
            unsigned t = bsums[i];
            bsums[i] = run;
            run += t;
        }
    }
}

__global__ void scan3_kernel(unsigned* __restrict__ cursor,
                             const unsigned* __restrict__ bsums, int n) {
    int i = blockIdx.x * 256 + threadIdx.x;
    if (i < n) cursor[i] += bsums[blockIdx.x];
}

// after this, cursor[n] == CSR end offset of node n (start = cursor[n-1], or 0)
__global__ void scatter_ids_kernel(const int* __restrict__ eidx,
                                   unsigned* __restrict__ cursor,
                                   unsigned* __restrict__ sorted, int E) {
    int e = blockIdx.x * blockDim.x + threadIdx.x;
    if (e < E) {
        unsigned pos = atomicAdd(&cursor[eidx[2 * e]], 1u);
        sorted[pos] = (unsigned)e;
    }
}

// ---- phase 2: compute message rows for edges [lo, hi), store to msgs ----
__launch_bounds__(256, 2)
__global__ void edge_msg_kernel(const float* __restrict__ nodes,
                                const float* __restrict__ edges,
                                const int*   __restrict__ eidx,
                                const float* __restrict__ W1,
                                const float* __restrict__ b1,
                                const float* __restrict__ W2,
                                const float* __restrict__ b2,
                                float* __restrict__ msgs,
                                int lo, int hi) {
    int e = lo + blockIdx.x * 256 + threadIdx.x;
    if (e >= hi) return;

    int nt = eidx[2 * e + 1];   // gather source (ends)

    // ---- GEMM1: h1 = ssp(edges[e] @ W1 + b1) ----
    float h1[DD];
    #pragma unroll
    for (int d = 0; d < DD; ++d) h1[d] = b1[d];

    const float4* ev4 = reinterpret_cast<const float4*>(edges) + (size_t)e * (FF / 4);
    #pragma unroll 1
    for (int f4 = 0; f4 < FF / 4; ++f4) {
        float4 ev = ev4[f4];
        const float* w0 = W1 + (size_t)(f4 * 4) * DD;
        #pragma unroll
        for (int d = 0; d < DD; ++d) h1[d] = fmaf(ev.x, w0[d], h1[d]);
        #pragma unroll
        for (int d = 0; d < DD; ++d) h1[d] = fmaf(ev.y, w0[DD + d], h1[d]);
        #pragma unroll
        for (int d = 0; d < DD; ++d) h1[d] = fmaf(ev.z, w0[2 * DD + d], h1[d]);
        #pragma unroll
        for (int d = 0; d < DD; ++d) h1[d] = fmaf(ev.w, w0[3 * DD + d], h1[d]);
    }

    #pragma unroll
    for (int d = 0; d < DD; ++d) h1[d] = ssp_f(h1[d]);

    const float4* nrow4 = reinterpret_cast<const float4*>(nodes + (size_t)nt * DD);
    float4*       mrow4 = reinterpret_cast<float4*>(msgs + (size_t)(e - lo) * DD);

    // ---- GEMM2 in two 64-wide output chunks to bound VGPR pressure ----
    #pragma unroll 1
    for (int c = 0; c < 2; ++c) {
        const int base = c * 64;
        float h2[64];
        #pragma unroll
        for (int j = 0; j < 64; ++j) h2[j] = b2[base + j];

        #pragma unroll
        for (int k = 0; k < DD; ++k) {
            float hk = h1[k];
            const float* w = W2 + (size_t)k * DD + base;
            #pragma unroll
            for (int j = 0; j < 64; ++j) h2[j] = fmaf(hk, w[j], h2[j]);
        }

        #pragma unroll
        for (int j4 = 0; j4 < 16; ++j4) {
            float4 nv = nrow4[c * 16 + j4];
            float4 v;
            v.x = ssp_f(h2[4 * j4 + 0]) * nv.x;
            v.y = ssp_f(h2[4 * j4 + 1]) * nv.y;
            v.z = ssp_f(h2[4 * j4 + 2]) * nv.z;
            v.w = ssp_f(h2[4 * j4 + 3]) * nv.w;
            mrow4[c * 16 + j4] = v;
        }
    }
}

// ---- phase 3: per-node segment reduce over sorted edge list, no atomics ----
__global__ void node_reduce_kernel(const float* __restrict__ msgs,
                                   const unsigned* __restrict__ sorted,
                                   const unsigned* __restrict__ ends,
                                   float* __restrict__ out,
                                   int N, int lo, int hi) {
    int n = blockIdx.x * 2 + (threadIdx.x >> 7);
    if (n >= N) return;
    int d = threadIdx.x & 127;

    unsigned s    = (n == 0) ? 0u : ends[n - 1];
    unsigned epos = ends[n];

    float acc = 0.0f;
    for (unsigned i = s; i < epos; ++i) {
        int j = (int)sorted[i];
        if (j >= lo && j < hi)
            acc += msgs[(size_t)(j - lo) * DD + d];
    }
    if (epos > s) out[(size_t)n * DD + d] += acc;
}

// ---- fallback: original fused atomic kernel (used only if ws too small) ----
__launch_bounds__(256, 2)
__global__ void edge_fused_atomic_kernel(const float* __restrict__ nodes,
                                         const float* __restrict__ edges,
                                         const int*   __restrict__ eidx,
                                         const float* __restrict__ W1,
                                         const float* __restrict__ b1,
                                         const float* __restrict__ W2,
                                         const float* __restrict__ b2,
                                         float* __restrict__ out, int E) {
    int e = blockIdx.x * 256 + threadIdx.x;
    if (e >= E) return;
    int ns = eidx[2 * e + 0];
    int nt = eidx[2 * e + 1];

    float h1[DD];
    #pragma unroll
    for (int d = 0; d < DD; ++d) h1[d] = b1[d];
    const float4* ev4 = reinterpret_cast<const float4*>(edges) + (size_t)e * (FF / 4);
    #pragma unroll 1
    for (int f4 = 0; f4 < FF / 4; ++f4) {
        float4 ev = ev4[f4];
        const float* w0 = W1 + (size_t)(f4 * 4) * DD;
        #pragma unroll
        for (int d = 0; d < DD; ++d) h1[d] = fmaf(ev.x, w0[d], h1[d]);
        #pragma unroll
        for (int d = 0; d < DD; ++d) h1[d] = fmaf(ev.y, w0[DD + d], h1[d]);
        #pragma unroll
        for (int d = 0; d < DD; ++d) h1[d] = fmaf(ev.z, w0[2 * DD + d], h1[d]);
        #pragma unroll
        for (int d = 0; d < DD; ++d) h1[d] = fmaf(ev.w, w0[3 * DD + d], h1[d]);
    }
    #pragma unroll
    for (int d = 0; d < DD; ++d) h1[d] = ssp_f(h1[d]);

    const float* nrow = nodes + (size_t)nt * DD;
    float*       orow = out   + (size_t)ns * DD;
    #pragma unroll 1
    for (int c = 0; c < 2; ++c) {
        const int base = c * 64;
        float h2[64];
        #pragma unroll
        for (int j = 0; j < 64; ++j) h2[j] = b2[base + j];
        #pragma unroll
        for (int k = 0; k < DD; ++k) {
            float hk = h1[k];
            const float* w = W2 + (size_t)k * DD + base;
            #pragma unroll
            for (int j = 0; j < 64; ++j) h2[j] = fmaf(hk, w[j], h2[j]);
        }
        #pragma unroll
        for (int j = 0; j < 64; ++j) {
            float m = ssp_f(h2[j]) * nrow[base + j];
            __hip_atomic_fetch_add(&orow[base + j], m,
                                   __ATOMIC_RELAXED, __HIP_MEMORY_SCOPE_AGENT);
        }
    }
}

extern "C" void kernel_launch(void* const* d_in, const int* in_sizes, int n_in,
                              void* d_out, int out_size, void* d_ws, size_t ws_size,
                              hipStream_t stream) {
    const float* nodes = (const float*)d_in[0];
    const float* edges = (const float*)d_in[1];
    const int*   eidx  = (const int*)  d_in[2];
    const float* W1    = (const float*)d_in[3];
    const float* b1    = (const float*)d_in[4];
    const float* W2    = (const float*)d_in[5];
    const float* b2    = (const float*)d_in[6];
    float* out = (float*)d_out;

    int ND = in_sizes[0];        // N*D
    int N  = ND / DD;            // 100000
    int E  = in_sizes[1] / FF;   // 600000

    // out = nodes
    copy_nodes_kernel<<<dim3(1024), dim3(256), 0, stream>>>(
        (const float4*)nodes, (float4*)out, ND / 4);

    // ---- workspace layout ----
    int nb = (N + 255) / 256;
    size_t sort_elems = (size_t)2 * N + nb + E;       // counts, cursor, bsums, sorted
    size_t sort_bytes = sort_elems * sizeof(unsigned);
    size_t msg_avail  = (ws_size > sort_bytes + 256) ? (ws_size - sort_bytes - 256) : 0;
    long long Ec_ll   = (long long)(msg_avail / (DD * sizeof(float)));
    int Ec = (Ec_ll > E) ? E : (int)Ec_ll;

    bool fast_path = (Ec >= 8192);
    if (!fast_path) {
        edge_fused_atomic_kernel<<<dim3((E + 255) / 256), dim3(256), 0, stream>>>(
            nodes, edges, eidx, W1, b1, W2, b2, out, E);
        return;
    }

    unsigned* counts = (unsigned*)d_ws;
    unsigned* cursor = counts + N;
    unsigned* bsums  = cursor + N;
    unsigned* sorted = bsums + nb;
    float*    msgs   = (float*)(((uintptr_t)(sorted + E) + 255) & ~(uintptr_t)255);

    // ---- counting sort by start node -> sorted ids + CSR end offsets ----
    zero_u32_kernel<<<dim3(256), dim3(256), 0, stream>>>(counts, N);
    hist_kernel<<<dim3((E + 255) / 256), dim3(256), 0, stream>>>(eidx, counts, E);
    scan1_kernel<<<dim3(nb), dim3(256), 0, stream>>>(counts, cursor, bsums, N);
    scan2_kernel<<<dim3(1), dim3(64), 0, stream>>>(bsums, nb);
    scan3_kernel<<<dim3(nb), dim3(256), 0, stream>>>(cursor, bsums, N);
    scatter_ids_kernel<<<dim3((E + 255) / 256), dim3(256), 0, stream>>>(eidx, cursor, sorted, E);
    // cursor[] now holds CSR end offsets

    // ---- chunked: compute msgs then segment-reduce, no atomics ----
    for (int lo = 0; lo < E; lo += Ec) {
        int hi = (lo + Ec < E) ? lo + Ec : E;
        int ne = hi - lo;
        edge_msg_kernel<<<dim3((ne + 255) / 256), dim3(256), 0, stream>>>(
            nodes, edges, eidx, W1, b1, W2, b2, msgs, lo, hi);
        node_reduce_kernel<<<dim3((N + 1) / 2), dim3(256), 0, stream>>>(
            msgs, sorted, cursor, out, N, lo, hi);
    }
}

// Round 4
// 702.021 us; speedup vs baseline: 6.3151x; 2.7492x over previous
//
#include <hip/hip_runtime.h>
#include <math.h>

#define DD 128   // node / hidden dim
#define FF 64    // edge feature dim
#define BM 64    // edges per block (MFMA kernel)

typedef __attribute__((ext_vector_type(8))) short bf16x8;
typedef __attribute__((ext_vector_type(4))) short short4s;
typedef __attribute__((ext_vector_type(4))) float f32x4;

__device__ __forceinline__ float ssp_f(float x) {
    float ax = fabsf(x);
    float e  = __expf(-ax);
    return fmaxf(x, 0.0f) + __logf(1.0f + e) - 0.6931471805599453f;
}

__device__ __forceinline__ unsigned short f2bf(float f) {
    unsigned u = __float_as_uint(f);
    unsigned r = (u + 0x7FFFu + ((u >> 16) & 1u)) >> 16;
    return (unsigned short)r;
}
__device__ __forceinline__ float bf2f(unsigned short h) {
    return __uint_as_float(((unsigned)h) << 16);
}

__global__ void copy_nodes_kernel(const float4* __restrict__ src,
                                  float4* __restrict__ dst, int n4) {
    int i = blockIdx.x * blockDim.x + threadIdx.x;
    int stride = gridDim.x * blockDim.x;
    for (; i < n4; i += stride) dst[i] = src[i];
}

__global__ void zero_u32_kernel(unsigned* __restrict__ p, int n) {
    int i = blockIdx.x * blockDim.x + threadIdx.x;
    int stride = gridDim.x * blockDim.x;
    for (; i < n; i += stride) p[i] = 0u;
}

__global__ void hist_kernel(const int* __restrict__ eidx,
                            unsigned* __restrict__ counts, int E) {
    int e = blockIdx.x * blockDim.x + threadIdx.x;
    if (e < E) atomicAdd(&counts[eidx[2 * e]], 1u);
}

__global__ void scan1_kernel(const unsigned* __restrict__ counts,
                             unsigned* __restrict__ cursor,
                             unsigned* __restrict__ bsums, int n) {
    __shared__ unsigned s[256];
    int i = blockIdx.x * 256 + threadIdx.x;
    unsigned v = (i < n) ? counts[i] : 0u;
    s[threadIdx.x] = v;
    __syncthreads();
    #pragma unroll
    for (int d = 1; d < 256; d <<= 1) {
        unsigned t = (threadIdx.x >= d) ? s[threadIdx.x - d] : 0u;
        __syncthreads();
        s[threadIdx.x] += t;
        __syncthreads();
    }
    if (i < n) cursor[i] = s[threadIdx.x] - v;
    if (threadIdx.x == 255) bsums[blockIdx.x] = s[255];
}

__global__ void scan2_kernel(unsigned* __restrict__ bsums, int nb) {
    if (threadIdx.x == 0 && blockIdx.x == 0) {
        unsigned run = 0u;
        for (int i = 0; i < nb; ++i) {
            unsigned t = bsums[i];
            bsums[i] = run;
            run += t;
        }
    }
}

__global__ void scan3_kernel(unsigned* __restrict__ cursor,
                             const unsigned* __restrict__ bsums, int n) {
    int i = blockIdx.x * 256 + threadIdx.x;
    if (i < n) cursor[i] += bsums[blockIdx.x];
}

__global__ void scatter_ids_kernel(const int* __restrict__ eidx,
                                   unsigned* __restrict__ cursor,
                                   unsigned* __restrict__ sorted, int E) {
    int e = blockIdx.x * blockDim.x + threadIdx.x;
    if (e < E) {
        unsigned pos = atomicAdd(&cursor[eidx[2 * e]], 1u);
        sorted[pos] = (unsigned)e;
    }
}

// ---- prep: split W[K][128] into bf16 hi/lo, laid out in MFMA B-fragment
// order: chunk (j, s, lane) holds W[k = s*32 + (lane>>4)*8 + i][j*16 + (lane&15)]
__global__ void prep_w_kernel(const float* __restrict__ W, int K,
                              unsigned short* __restrict__ hi,
                              unsigned short* __restrict__ lo) {
    int S = K >> 5;
    int idx = blockIdx.x * blockDim.x + threadIdx.x;
    int total = 8 * S * 64;
    if (idx >= total) return;
    int l = idx & 63;
    int s = (idx >> 6) % S;
    int j = idx / (64 * S);
    int col = j * 16 + (l & 15);
    int kbase = s * 32 + (l >> 4) * 8;
    int ob = ((j * S + s) * 64 + l) * 8;
    #pragma unroll
    for (int i = 0; i < 8; ++i) {
        float w = W[(size_t)(kbase + i) * DD + col];
        unsigned short h = f2bf(w);
        hi[ob + i] = h;
        lo[ob + i] = f2bf(w - bf2f(h));
    }
}

// ---- phase 2: MFMA fused GEMM1+GEMM2+gather-multiply, bf16 split-3 ----
__launch_bounds__(256, 2)
__global__ void edge_mfma_kernel(const float* __restrict__ nodes,
                                 const float* __restrict__ edges,
                                 const int*   __restrict__ eidx,
                                 const unsigned short* __restrict__ W1h,
                                 const unsigned short* __restrict__ W1l,
                                 const unsigned short* __restrict__ W2h,
                                 const unsigned short* __restrict__ W2l,
                                 const float* __restrict__ b1,
                                 const float* __restrict__ b2,
                                 float* __restrict__ msgs,
                                 int lo, int hi) {
    __shared__ unsigned short aHi[BM * FF];   // 8 KB
    __shared__ unsigned short aLo[BM * FF];   // 8 KB
    __shared__ unsigned short fHi[BM * DD];   // 16 KB
    __shared__ unsigned short fLo[BM * DD];   // 16 KB

    const int t = threadIdx.x;
    const int tile_lo = lo + blockIdx.x * BM;

    // ---- stage edges tile [64][64] fp32 -> bf16 hi/lo, XOR-swizzled ----
    const float4* e4 = reinterpret_cast<const float4*>(edges);
    #pragma unroll
    for (int it = 0; it < 4; ++it) {
        int idx = it * 256 + t;
        int row = idx >> 4, c4 = idx & 15;
        int e = tile_lo + row;
        float4 v = make_float4(0.f, 0.f, 0.f, 0.f);
        if (e < hi) v = e4[(size_t)e * (FF / 4) + c4];
        unsigned short h0 = f2bf(v.x), h1 = f2bf(v.y), h2 = f2bf(v.z), h3 = f2bf(v.w);
        short4s hv = { (short)h0, (short)h1, (short)h2, (short)h3 };
        short4s lv = { (short)f2bf(v.x - bf2f(h0)), (short)f2bf(v.y - bf2f(h1)),
                       (short)f2bf(v.z - bf2f(h2)), (short)f2bf(v.w - bf2f(h3)) };
        int g = c4 >> 1, half = c4 & 1;
        int off = row * FF + ((g ^ (row & 7)) * 8) + half * 4;
        *reinterpret_cast<short4s*>(aHi + off) = hv;
        *reinterpret_cast<short4s*>(aLo + off) = lv;
    }
    __syncthreads();

    const int lane = t & 63, wave = t >> 6;
    const int wrow = wave * 16;            // wave's 16 output rows
    const int lr = lane & 15, lg = lane >> 4;

    // ---- GEMM1: [64x64] x [64x128], K-steps s=0,1 ----
    bf16x8 a1h[2], a1l[2];
    #pragma unroll
    for (int s = 0; s < 2; ++s) {
        int row = wrow + lr;
        int g = s * 4 + lg;
        int off = row * FF + ((g ^ (row & 7)) * 8);
        a1h[s] = *reinterpret_cast<const bf16x8*>(aHi + off);
        a1l[s] = *reinterpret_cast<const bf16x8*>(aLo + off);
    }
    f32x4 zero4 = { 0.f, 0.f, 0.f, 0.f };
    f32x4 acc1[8];
    #pragma unroll
    for (int j = 0; j < 8; ++j) acc1[j] = zero4;
    #pragma unroll
    for (int j = 0; j < 8; ++j) {
        #pragma unroll
        for (int s = 0; s < 2; ++s) {
            bf16x8 bh = *reinterpret_cast<const bf16x8*>(W1h + ((j * 2 + s) * 64 + lane) * 8);
            bf16x8 bl = *reinterpret_cast<const bf16x8*>(W1l + ((j * 2 + s) * 64 + lane) * 8);
            acc1[j] = __builtin_amdgcn_mfma_f32_16x16x32_bf16(a1h[s], bh, acc1[j], 0, 0, 0);
            acc1[j] = __builtin_amdgcn_mfma_f32_16x16x32_bf16(a1h[s], bl, acc1[j], 0, 0, 0);
            acc1[j] = __builtin_amdgcn_mfma_f32_16x16x32_bf16(a1l[s], bh, acc1[j], 0, 0, 0);
        }
    }

    // ---- epilogue1: bias + ssp + split -> F1 LDS (swizzled) ----
    #pragma unroll
    for (int j = 0; j < 8; ++j) {
        int col = j * 16 + lr;
        float bv = b1[col];
        #pragma unroll
        for (int r = 0; r < 4; ++r) {
            int row = wrow + lg * 4 + r;   // verified C/D layout
            float f = ssp_f(acc1[j][r] + bv);
            unsigned short h = f2bf(f);
            unsigned short l2 = f2bf(f - bf2f(h));
            int off = row * DD + (((col >> 3) ^ (row & 7)) * 8) + (col & 7);
            fHi[off] = h;
            fLo[off] = l2;
        }
    }
    __syncthreads();

    // ---- GEMM2: [64x128] x [128x128], K-steps s=0..3 ----
    bf16x8 a2h[4], a2l[4];
    #pragma unroll
    for (int s = 0; s < 4; ++s) {
        int row = wrow + lr;
        int g = s * 4 + lg;
        int off = row * DD + ((g ^ (row & 7)) * 8);
        a2h[s] = *reinterpret_cast<const bf16x8*>(fHi + off);
        a2l[s] = *reinterpret_cast<const bf16x8*>(fLo + off);
    }
    f32x4 acc2[8];
    #pragma unroll
    for (int j = 0; j < 8; ++j) acc2[j] = zero4;
    #pragma unroll
    for (int j = 0; j < 8; ++j) {
        #pragma unroll
        for (int s = 0; s < 4; ++s) {
            bf16x8 bh = *reinterpret_cast<const bf16x8*>(W2h + ((j * 4 + s) * 64 + lane) * 8);
            bf16x8 bl = *reinterpret_cast<const bf16x8*>(W2l + ((j * 4 + s) * 64 + lane) * 8);
            acc2[j] = __builtin_amdgcn_mfma_f32_16x16x32_bf16(a2h[s], bh, acc2[j], 0, 0, 0);
            acc2[j] = __builtin_amdgcn_mfma_f32_16x16x32_bf16(a2h[s], bl, acc2[j], 0, 0, 0);
            acc2[j] = __builtin_amdgcn_mfma_f32_16x16x32_bf16(a2l[s], bh, acc2[j], 0, 0, 0);
        }
    }

    // ---- epilogue2: bias + ssp, gather nodes[ends], write msgs ----
    int ntid[4];
    #pragma unroll
    for (int r = 0; r < 4; ++r) {
        int e = tile_lo + wrow + lg * 4 + r;
        ntid[r] = (e < hi) ? eidx[2 * e + 1] : 0;
    }
    #pragma unroll
    for (int j = 0; j < 8; ++j) {
        int col = j * 16 + lr;
        float bv = b2[col];
        #pragma unroll
        for (int r = 0; r < 4; ++r) {
            int R = wrow + lg * 4 + r;
            int e = tile_lo + R;
            if (e < hi) {
                float f = ssp_f(acc2[j][r] + bv);
                float nv = nodes[(size_t)ntid[r] * DD + col];
                msgs[(size_t)(e - lo) * DD + col] = f * nv;
            }
        }
    }
}

// ---- phase 3: per-node segment reduce over sorted edge list, no atomics ----
__global__ void node_reduce_kernel(const float* __restrict__ msgs,
                                   const unsigned* __restrict__ sorted,
                                   const unsigned* __restrict__ ends,
                                   float* __restrict__ out,
                                   int N, int lo, int hi) {
    int n = blockIdx.x * 2 + (threadIdx.x >> 7);
    if (n >= N) return;
    int d = threadIdx.x & 127;

    unsigned s    = (n == 0) ? 0u : ends[n - 1];
    unsigned epos = ends[n];

    float acc = 0.0f;
    for (unsigned i = s; i < epos; ++i) {
        int j = (int)sorted[i];
        if (j >= lo && j < hi)
            acc += msgs[(size_t)(j - lo) * DD + d];
    }
    if (epos > s) out[(size_t)n * DD + d] += acc;
}

// ---- fallback: fused atomic kernel (used only if ws too small) ----
__launch_bounds__(256, 2)
__global__ void edge_fused_atomic_kernel(const float* __restrict__ nodes,
                                         const float* __restrict__ edges,
                                         const int*   __restrict__ eidx,
                                         const float* __restrict__ W1,
                                         const float* __restrict__ b1,
                                         const float* __restrict__ W2,
                                         const float* __restrict__ b2,
                                         float* __restrict__ out, int E) {
    int e = blockIdx.x * 256 + threadIdx.x;
    if (e >= E) return;
    int ns = eidx[2 * e + 0];
    int nt = eidx[2 * e + 1];

    float h1[DD];
    #pragma unroll
    for (int d = 0; d < DD; ++d) h1[d] = b1[d];
    const float4* ev4 = reinterpret_cast<const float4*>(edges) + (size_t)e * (FF / 4);
    #pragma unroll 1
    for (int f4 = 0; f4 < FF / 4; ++f4) {
        float4 ev = ev4[f4];
        const float* w0 = W1 + (size_t)(f4 * 4) * DD;
        #pragma unroll
        for (int d = 0; d < DD; ++d) h1[d] = fmaf(ev.x, w0[d], h1[d]);
        #pragma unroll
        for (int d = 0; d < DD; ++d) h1[d] = fmaf(ev.y, w0[DD + d], h1[d]);
        #pragma unroll
        for (int d = 0; d < DD; ++d) h1[d] = fmaf(ev.z, w0[2 * DD + d], h1[d]);
        #pragma unroll
        for (int d = 0; d < DD; ++d) h1[d] = fmaf(ev.w, w0[3 * DD + d], h1[d]);
    }
    #pragma unroll
    for (int d = 0; d < DD; ++d) h1[d] = ssp_f(h1[d]);

    const float* nrow = nodes + (size_t)nt * DD;
    float*       orow = out   + (size_t)ns * DD;
    #pragma unroll 1
    for (int c = 0; c < 2; ++c) {
        const int base = c * 64;
        float h2[64];
        #pragma unroll
        for (int j = 0; j < 64; ++j) h2[j] = b2[base + j];
        #pragma unroll
        for (int k = 0; k < DD; ++k) {
            float hk = h1[k];
            const float* w = W2 + (size_t)k * DD + base;
            #pragma unroll
            for (int j = 0; j < 64; ++j) h2[j] = fmaf(hk, w[j], h2[j]);
        }
        #pragma unroll
        for (int j = 0; j < 64; ++j) {
            float m = ssp_f(h2[j]) * nrow[base + j];
            __hip_atomic_fetch_add(&orow[base + j], m,
                                   __ATOMIC_RELAXED, __HIP_MEMORY_SCOPE_AGENT);
        }
    }
}

extern "C" void kernel_launch(void* const* d_in, const int* in_sizes, int n_in,
                              void* d_out, int out_size, void* d_ws, size_t ws_size,
                              hipStream_t stream) {
    const float* nodes = (const float*)d_in[0];
    const float* edges = (const float*)d_in[1];
    const int*   eidx  = (const int*)  d_in[2];
    const float* W1    = (const float*)d_in[3];
    const float* b1    = (const float*)d_in[4];
    const float* W2    = (const float*)d_in[5];
    const float* b2    = (const float*)d_in[6];
    float* out = (float*)d_out;

    int ND = in_sizes[0];        // N*D
    int N  = ND / DD;            // 100000
    int E  = in_sizes[1] / FF;   // 600000

    // out = nodes
    copy_nodes_kernel<<<dim3(1024), dim3(256), 0, stream>>>(
        (const float4*)nodes, (float4*)out, ND / 4);

    // ---- workspace layout: sort | W-frag buffers | msgs chunk ----
    int nb = (N + 255) / 256;
    size_t sort_bytes = ((size_t)2 * N + nb + E) * sizeof(unsigned);
    uintptr_t base = (uintptr_t)d_ws;
    uintptr_t pw = (base + sort_bytes + 255) & ~(uintptr_t)255;
    size_t w_elems = (size_t)FF * DD * 2 + (size_t)DD * DD * 2;  // hi+lo for W1,W2
    uintptr_t pm = (pw + w_elems * 2 + 255) & ~(uintptr_t)255;
    size_t msg_avail = (base + ws_size > pm) ? (size_t)(base + ws_size - pm) : 0;
    long long Ec_ll = (long long)(msg_avail / (DD * sizeof(float)));
    int Ec = (Ec_ll > E) ? E : (int)Ec_ll;
    Ec &= ~(BM - 1);             // multiple of tile size

    if (Ec < 8192) {
        edge_fused_atomic_kernel<<<dim3((E + 255) / 256), dim3(256), 0, stream>>>(
            nodes, edges, eidx, W1, b1, W2, b2, out, E);
        return;
    }

    unsigned* counts = (unsigned*)d_ws;
    unsigned* cursor = counts + N;
    unsigned* bsums  = cursor + N;
    unsigned* sorted = bsums + nb;
    unsigned short* W1h = (unsigned short*)pw;
    unsigned short* W1l = W1h + (size_t)FF * DD;
    unsigned short* W2h = W1l + (size_t)FF * DD;
    unsigned short* W2l = W2h + (size_t)DD * DD;
    float* msgs = (float*)pm;

    // ---- prep weight fragments (bf16 split, MFMA B layout) ----
    prep_w_kernel<<<dim3(4), dim3(256), 0, stream>>>(W1, FF, W1h, W1l);   // 1024 thr
    prep_w_kernel<<<dim3(8), dim3(256), 0, stream>>>(W2, DD, W2h, W2l);   // 2048 thr

    // ---- counting sort by start node -> sorted ids + CSR end offsets ----
    zero_u32_kernel<<<dim3(256), dim3(256), 0, stream>>>(counts, N);
    hist_kernel<<<dim3((E + 255) / 256), dim3(256), 0, stream>>>(eidx, counts, E);
    scan1_kernel<<<dim3(nb), dim3(256), 0, stream>>>(counts, cursor, bsums, N);
    scan2_kernel<<<dim3(1), dim3(64), 0, stream>>>(bsums, nb);
    scan3_kernel<<<dim3(nb), dim3(256), 0, stream>>>(cursor, bsums, N);
    scatter_ids_kernel<<<dim3((E + 255) / 256), dim3(256), 0, stream>>>(eidx, cursor, sorted, E);

    // ---- chunked: MFMA msgs then segment-reduce, no atomics ----
    for (int lo = 0; lo < E; lo += Ec) {
        int hi = (lo + Ec < E) ? lo + Ec : E;
        int ne = hi - lo;
        edge_mfma_kernel<<<dim3((ne + BM - 1) / BM), dim3(256), 0, stream>>>(
            nodes, edges, eidx, W1h, W1l, W2h, W2l, b1, b2, msgs, lo, hi);
        node_reduce_kernel<<<dim3((N + 1) / 2), dim3(256), 0, stream>>>(
            msgs, sorted, cursor, out, N, lo, hi);
    }
}

// Round 5
// 510.485 us; speedup vs baseline: 8.6846x; 1.3752x over previous
//
#include <hip/hip_runtime.h>
#include <math.h>

#define DD 128   // node / hidden dim
#define FF 64    // edge feature dim
#define BM 64    // edges per block (MFMA kernel)

typedef __attribute__((ext_vector_type(8))) short bf16x8;
typedef __attribute__((ext_vector_type(4))) short short4s;
typedef __attribute__((ext_vector_type(4))) float f32x4;

__device__ __forceinline__ float ssp_f(float x) {
    float ax = fabsf(x);
    float e  = __expf(-ax);
    return fmaxf(x, 0.0f) + __logf(1.0f + e) - 0.6931471805599453f;
}

__device__ __forceinline__ unsigned short f2bf(float f) {
    unsigned u = __float_as_uint(f);
    unsigned r = (u + 0x7FFFu + ((u >> 16) & 1u)) >> 16;
    return (unsigned short)r;
}
__device__ __forceinline__ float bf2f(unsigned short h) {
    return __uint_as_float(((unsigned)h) << 16);
}

__global__ void copy_nodes_kernel(const float4* __restrict__ src,
                                  float4* __restrict__ dst, int n4) {
    int i = blockIdx.x * blockDim.x + threadIdx.x;
    int stride = gridDim.x * blockDim.x;
    for (; i < n4; i += stride) dst[i] = src[i];
}

__global__ void zero_u32_kernel(unsigned* __restrict__ p, int n) {
    int i = blockIdx.x * blockDim.x + threadIdx.x;
    int stride = gridDim.x * blockDim.x;
    for (; i < n; i += stride) p[i] = 0u;
}

__global__ void hist_kernel(const int* __restrict__ eidx,
                            unsigned* __restrict__ counts, int E) {
    int e = blockIdx.x * blockDim.x + threadIdx.x;
    if (e < E) atomicAdd(&counts[eidx[2 * e]], 1u);
}

__global__ void scan1_kernel(const unsigned* __restrict__ counts,
                             unsigned* __restrict__ cursor,
                             unsigned* __restrict__ bsums, int n) {
    __shared__ unsigned s[256];
    int i = blockIdx.x * 256 + threadIdx.x;
    unsigned v = (i < n) ? counts[i] : 0u;
    s[threadIdx.x] = v;
    __syncthreads();
    #pragma unroll
    for (int d = 1; d < 256; d <<= 1) {
        unsigned t = (threadIdx.x >= d) ? s[threadIdx.x - d] : 0u;
        __syncthreads();
        s[threadIdx.x] += t;
        __syncthreads();
    }
    if (i < n) cursor[i] = s[threadIdx.x] - v;
    if (threadIdx.x == 255) bsums[blockIdx.x] = s[255];
}

// parallel exclusive scan of block sums (nb <= 512 fast path)
__global__ void scan2_kernel(unsigned* __restrict__ bsums, int nb) {
    __shared__ unsigned s[512];
    int t = threadIdx.x;
    if (nb <= 512) {
        unsigned v = (t < nb) ? bsums[t] : 0u;
        s[t] = v;
        __syncthreads();
        #pragma unroll
        for (int d = 1; d < 512; d <<= 1) {
            unsigned x = (t >= d) ? s[t - d] : 0u;
            __syncthreads();
            s[t] += x;
            __syncthreads();
        }
        if (t < nb) bsums[t] = s[t] - v;   // exclusive
    } else if (t == 0) {
        unsigned run = 0u;
        for (int i = 0; i < nb; ++i) { unsigned x = bsums[i]; bsums[i] = run; run += x; }
    }
}

__global__ void scan3_kernel(unsigned* __restrict__ cursor,
                             const unsigned* __restrict__ bsums, int n) {
    int i = blockIdx.x * 256 + threadIdx.x;
    if (i < n) cursor[i] += bsums[blockIdx.x];
}

// after this, cursor[n] == CSR end offset of node n; sorted_e = edge ids in
// start-node order, sorted_nt = corresponding end-node (gather source) ids
__global__ void scatter_ids_kernel(const int* __restrict__ eidx,
                                   unsigned* __restrict__ cursor,
                                   unsigned* __restrict__ sorted_e,
                                   unsigned* __restrict__ sorted_nt, int E) {
    int e = blockIdx.x * blockDim.x + threadIdx.x;
    if (e < E) {
        unsigned pos = atomicAdd(&cursor[eidx[2 * e]], 1u);
        sorted_e[pos]  = (unsigned)e;
        sorted_nt[pos] = (unsigned)eidx[2 * e + 1];
    }
}

// ---- prep: split W[K][128] into bf16 hi/lo, MFMA B-fragment order ----
__global__ void prep_w_kernel(const float* __restrict__ W, int K,
                              unsigned short* __restrict__ hi,
                              unsigned short* __restrict__ lo) {
    int S = K >> 5;
    int idx = blockIdx.x * blockDim.x + threadIdx.x;
    int total = 8 * S * 64;
    if (idx >= total) return;
    int l = idx & 63;
    int s = (idx >> 6) % S;
    int j = idx / (64 * S);
    int col = j * 16 + (l & 15);
    int kbase = s * 32 + (l >> 4) * 8;
    int ob = ((j * S + s) * 64 + l) * 8;
    #pragma unroll
    for (int i = 0; i < 8; ++i) {
        float w = W[(size_t)(kbase + i) * DD + col];
        unsigned short h = f2bf(w);
        hi[ob + i] = h;
        lo[ob + i] = f2bf(w - bf2f(h));
    }
}

// ---- phase 2: MFMA fused GEMM1+GEMM2+gather-multiply, sorted order ----
// LDS: A-tile (16KB) is dead after fragment loads; F1 tile (32KB) overlays it.
__launch_bounds__(256, 2)
__global__ void edge_mfma_kernel(const float* __restrict__ nodes,
                                 const float* __restrict__ edges,
                                 const unsigned* __restrict__ sorted_e,
                                 const unsigned* __restrict__ sorted_nt,
                                 const unsigned short* __restrict__ W1h,
                                 const unsigned short* __restrict__ W1l,
                                 const unsigned short* __restrict__ W2h,
                                 const unsigned short* __restrict__ W2l,
                                 const float* __restrict__ b1,
                                 const float* __restrict__ b2,
                                 float* __restrict__ msgs,
                                 int lo, int hi) {
    __shared__ unsigned short smem[BM * DD * 2];   // 32 KB, aliased
    unsigned short* aHi = smem;                    // BM*FF
    unsigned short* aLo = smem + BM * FF;
    unsigned short* fHi = smem;                    // BM*DD (overlays A)
    unsigned short* fLo = smem + BM * DD;

    const int t = threadIdx.x;
    const int tile_lo = lo + blockIdx.x * BM;      // sorted-index base

    // ---- stage edges tile (gathered by sorted id) fp32->bf16 hi/lo, swizzled
    const float4* e4 = reinterpret_cast<const float4*>(edges);
    #pragma unroll
    for (int it = 0; it < 4; ++it) {
        int idx = it * 256 + t;
        int row = idx >> 4, c4 = idx & 15;
        int i = tile_lo + row;
        float4 v = make_float4(0.f, 0.f, 0.f, 0.f);
        if (i < hi) {
            unsigned e = sorted_e[i];
            v = e4[(size_t)e * (FF / 4) + c4];
        }
        unsigned short h0 = f2bf(v.x), h1 = f2bf(v.y), h2 = f2bf(v.z), h3 = f2bf(v.w);
        short4s hv = { (short)h0, (short)h1, (short)h2, (short)h3 };
        short4s lv = { (short)f2bf(v.x - bf2f(h0)), (short)f2bf(v.y - bf2f(h1)),
                       (short)f2bf(v.z - bf2f(h2)), (short)f2bf(v.w - bf2f(h3)) };
        int g = c4 >> 1, half = c4 & 1;
        int off = row * FF + ((g ^ (row & 7)) * 8) + half * 4;
        *reinterpret_cast<short4s*>(aHi + off) = hv;
        *reinterpret_cast<short4s*>(aLo + off) = lv;
    }
    __syncthreads();

    const int lane = t & 63, wave = t >> 6;
    const int wrow = wave * 16;
    const int lr = lane & 15, lg = lane >> 4;

    // ---- load GEMM1 A-fragments, then free the A LDS region ----
    bf16x8 a1h[2], a1l[2];
    #pragma unroll
    for (int s = 0; s < 2; ++s) {
        int row = wrow + lr;
        int g = s * 4 + lg;
        int off = row * FF + ((g ^ (row & 7)) * 8);
        a1h[s] = *reinterpret_cast<const bf16x8*>(aHi + off);
        a1l[s] = *reinterpret_cast<const bf16x8*>(aLo + off);
    }
    __syncthreads();   // all waves done reading A; F1 may overwrite

    // ---- GEMM1: [64x64] x [64x128], split-3 ----
    f32x4 zero4 = { 0.f, 0.f, 0.f, 0.f };
    f32x4 acc1[8];
    #pragma unroll
    for (int j = 0; j < 8; ++j) acc1[j] = zero4;
    #pragma unroll
    for (int j = 0; j < 8; ++j) {
        #pragma unroll
        for (int s = 0; s < 2; ++s) {
            bf16x8 bh = *reinterpret_cast<const bf16x8*>(W1h + ((j * 2 + s) * 64 + lane) * 8);
            bf16x8 bl = *reinterpret_cast<const bf16x8*>(W1l + ((j * 2 + s) * 64 + lane) * 8);
            acc1[j] = __builtin_amdgcn_mfma_f32_16x16x32_bf16(a1h[s], bh, acc1[j], 0, 0, 0);
            acc1[j] = __builtin_amdgcn_mfma_f32_16x16x32_bf16(a1h[s], bl, acc1[j], 0, 0, 0);
            acc1[j] = __builtin_amdgcn_mfma_f32_16x16x32_bf16(a1l[s], bh, acc1[j], 0, 0, 0);
        }
    }

    // ---- epilogue1: bias + ssp + split -> F1 LDS (swizzled, aliased) ----
    #pragma unroll
    for (int j = 0; j < 8; ++j) {
        int col = j * 16 + lr;
        float bv = b1[col];
        #pragma unroll
        for (int r = 0; r < 4; ++r) {
            int row = wrow + lg * 4 + r;
            float f = ssp_f(acc1[j][r] + bv);
            unsigned short h = f2bf(f);
            unsigned short l2 = f2bf(f - bf2f(h));
            int off = row * DD + (((col >> 3) ^ (row & 7)) * 8) + (col & 7);
            fHi[off] = h;
            fLo[off] = l2;
        }
    }
    __syncthreads();

    // ---- GEMM2: [64x128] x [128x128], split-3 ----
    bf16x8 a2h[4], a2l[4];
    #pragma unroll
    for (int s = 0; s < 4; ++s) {
        int row = wrow + lr;
        int g = s * 4 + lg;
        int off = row * DD + ((g ^ (row & 7)) * 8);
        a2h[s] = *reinterpret_cast<const bf16x8*>(fHi + off);
        a2l[s] = *reinterpret_cast<const bf16x8*>(fLo + off);
    }
    f32x4 acc2[8];
    #pragma unroll
    for (int j = 0; j < 8; ++j) acc2[j] = zero4;
    #pragma unroll
    for (int j = 0; j < 8; ++j) {
        #pragma unroll
        for (int s = 0; s < 4; ++s) {
            bf16x8 bh = *reinterpret_cast<const bf16x8*>(W2h + ((j * 4 + s) * 64 + lane) * 8);
            bf16x8 bl = *reinterpret_cast<const bf16x8*>(W2l + ((j * 4 + s) * 64 + lane) * 8);
            acc2[j] = __builtin_amdgcn_mfma_f32_16x16x32_bf16(a2h[s], bh, acc2[j], 0, 0, 0);
            acc2[j] = __builtin_amdgcn_mfma_f32_16x16x32_bf16(a2h[s], bl, acc2[j], 0, 0, 0);
            acc2[j] = __builtin_amdgcn_mfma_f32_16x16x32_bf16(a2l[s], bh, acc2[j], 0, 0, 0);
        }
    }

    // ---- epilogue2: bias + ssp, gather nodes[end], write msgs at sorted pos
    int ntid[4];
    #pragma unroll
    for (int r = 0; r < 4; ++r) {
        int i = tile_lo + wrow + lg * 4 + r;
        ntid[r] = (i < hi) ? (int)sorted_nt[i] : 0;
    }
    #pragma unroll
    for (int j = 0; j < 8; ++j) {
        int col = j * 16 + lr;
        float bv = b2[col];
        #pragma unroll
        for (int r = 0; r < 4; ++r) {
            int R = wrow + lg * 4 + r;
            int i = tile_lo + R;
            if (i < hi) {
                float f = ssp_f(acc2[j][r] + bv);
                float nv = nodes[(size_t)ntid[r] * DD + col];
                msgs[(size_t)(i - lo) * DD + col] = f * nv;
            }
        }
    }
}

// ---- phase 3: contiguous segment reduce; fuses out = nodes + sum(msgs) ----
__global__ void node_reduce_kernel(const float4* __restrict__ msgs4,
                                   const unsigned* __restrict__ ends,
                                   const float4* __restrict__ nodes4,
                                   float4* __restrict__ out4,
                                   int N, int lo, int hi, int first) {
    int n = blockIdx.x * 8 + (threadIdx.x >> 5);
    if (n >= N) return;
    int d4 = threadIdx.x & 31;

    unsigned s = (n == 0) ? 0u : ends[n - 1];
    unsigned e = ends[n];
    unsigned cs = s < (unsigned)lo ? (unsigned)lo : s;
    unsigned ce = e > (unsigned)hi ? (unsigned)hi : e;

    float4 acc = make_float4(0.f, 0.f, 0.f, 0.f);
    for (unsigned i = cs; i < ce; ++i) {
        float4 m = msgs4[(size_t)(i - lo) * (DD / 4) + d4];
        acc.x += m.x; acc.y += m.y; acc.z += m.z; acc.w += m.w;
    }
    size_t o = (size_t)n * (DD / 4) + d4;
    if (first) {
        float4 nv = nodes4[o];
        out4[o] = make_float4(nv.x + acc.x, nv.y + acc.y, nv.z + acc.z, nv.w + acc.w);
    } else if (ce > cs) {
        float4 ov = out4[o];
        out4[o] = make_float4(ov.x + acc.x, ov.y + acc.y, ov.z + acc.z, ov.w + acc.w);
    }
}

// ---- fallback: fused atomic kernel (used only if ws too small) ----
__launch_bounds__(256, 2)
__global__ void edge_fused_atomic_kernel(const float* __restrict__ nodes,
                                         const float* __restrict__ edges,
                                         const int*   __restrict__ eidx,
                                         const float* __restrict__ W1,
                                         const float* __restrict__ b1,
                                         const float* __restrict__ W2,
                                         const float* __restrict__ b2,
                                         float* __restrict__ out, int E) {
    int e = blockIdx.x * 256 + threadIdx.x;
    if (e >= E) return;
    int ns = eidx[2 * e + 0];
    int nt = eidx[2 * e + 1];

    float h1[DD];
    #pragma unroll
    for (int d = 0; d < DD; ++d) h1[d] = b1[d];
    const float4* ev4 = reinterpret_cast<const float4*>(edges) + (size_t)e * (FF / 4);
    #pragma unroll 1
    for (int f4 = 0; f4 < FF / 4; ++f4) {
        float4 ev = ev4[f4];
        const float* w0 = W1 + (size_t)(f4 * 4) * DD;
        #pragma unroll
        for (int d = 0; d < DD; ++d) h1[d] = fmaf(ev.x, w0[d], h1[d]);
        #pragma unroll
        for (int d = 0; d < DD; ++d) h1[d] = fmaf(ev.y, w0[DD + d], h1[d]);
        #pragma unroll
        for (int d = 0; d < DD; ++d) h1[d] = fmaf(ev.z, w0[2 * DD + d], h1[d]);
        #pragma unroll
        for (int d = 0; d < DD; ++d) h1[d] = fmaf(ev.w, w0[3 * DD + d], h1[d]);
    }
    #pragma unroll
    for (int d = 0; d < DD; ++d) h1[d] = ssp_f(h1[d]);

    const float* nrow = nodes + (size_t)nt * DD;
    float*       orow = out   + (size_t)ns * DD;
    #pragma unroll 1
    for (int c = 0; c < 2; ++c) {
        const int base = c * 64;
        float h2[64];
        #pragma unroll
        for (int j = 0; j < 64; ++j) h2[j] = b2[base + j];
        #pragma unroll
        for (int k = 0; k < DD; ++k) {
            float hk = h1[k];
            const float* w = W2 + (size_t)k * DD + base;
            #pragma unroll
            for (int j = 0; j < 64; ++j) h2[j] = fmaf(hk, w[j], h2[j]);
        }
        #pragma unroll
        for (int j = 0; j < 64; ++j) {
            float m = ssp_f(h2[j]) * nrow[base + j];
            __hip_atomic_fetch_add(&orow[base + j], m,
                                   __ATOMIC_RELAXED, __HIP_MEMORY_SCOPE_AGENT);
        }
    }
}

extern "C" void kernel_launch(void* const* d_in, const int* in_sizes, int n_in,
                              void* d_out, int out_size, void* d_ws, size_t ws_size,
                              hipStream_t stream) {
    const float* nodes = (const float*)d_in[0];
    const float* edges = (const float*)d_in[1];
    const int*   eidx  = (const int*)  d_in[2];
    const float* W1    = (const float*)d_in[3];
    const float* b1    = (const float*)d_in[4];
    const float* W2    = (const float*)d_in[5];
    const float* b2    = (const float*)d_in[6];
    float* out = (float*)d_out;

    int ND = in_sizes[0];        // N*D
    int N  = ND / DD;            // 100000
    int E  = in_sizes[1] / FF;   // 600000

    // ---- workspace layout: sort | W-frag buffers | msgs chunk ----
    int nb = (N + 255) / 256;
    size_t sort_bytes = ((size_t)2 * N + nb + 2 * (size_t)E) * sizeof(unsigned);
    uintptr_t base = (uintptr_t)d_ws;
    uintptr_t pw = (base + sort_bytes + 255) & ~(uintptr_t)255;
    size_t w_elems = ((size_t)FF * DD + (size_t)DD * DD) * 2;   // hi+lo for W1,W2
    uintptr_t pm = (pw + w_elems * 2 + 255) & ~(uintptr_t)255;
    size_t msg_avail = (base + ws_size > pm) ? (size_t)(base + ws_size - pm) : 0;
    long long Ec_ll = (long long)(msg_avail / (DD * sizeof(float)));
    int Ec = (Ec_ll > E) ? E : (int)Ec_ll;
    Ec &= ~(BM - 1);

    if (Ec < 8192) {
        copy_nodes_kernel<<<dim3(1024), dim3(256), 0, stream>>>(
            (const float4*)nodes, (float4*)out, ND / 4);
        edge_fused_atomic_kernel<<<dim3((E + 255) / 256), dim3(256), 0, stream>>>(
            nodes, edges, eidx, W1, b1, W2, b2, out, E);
        return;
    }

    unsigned* counts    = (unsigned*)d_ws;
    unsigned* cursor    = counts + N;
    unsigned* bsums     = cursor + N;
    unsigned* sorted_e  = bsums + nb;
    unsigned* sorted_nt = sorted_e + E;
    unsigned short* W1h = (unsigned short*)pw;
    unsigned short* W1l = W1h + (size_t)FF * DD;
    unsigned short* W2h = W1l + (size_t)FF * DD;
    unsigned short* W2l = W2h + (size_t)DD * DD;
    float* msgs = (float*)pm;

    // ---- prep weight fragments (bf16 split, MFMA B layout) ----
    prep_w_kernel<<<dim3(4), dim3(256), 0, stream>>>(W1, FF, W1h, W1l);
    prep_w_kernel<<<dim3(8), dim3(256), 0, stream>>>(W2, DD, W2h, W2l);

    // ---- counting sort by start node -> sorted ids/nts + CSR end offsets ----
    zero_u32_kernel<<<dim3(256), dim3(256), 0, stream>>>(counts, N);
    hist_kernel<<<dim3((E + 255) / 256), dim3(256), 0, stream>>>(eidx, counts, E);
    scan1_kernel<<<dim3(nb), dim3(256), 0, stream>>>(counts, cursor, bsums, N);
    scan2_kernel<<<dim3(1), dim3(512), 0, stream>>>(bsums, nb);
    scan3_kernel<<<dim3(nb), dim3(256), 0, stream>>>(cursor, bsums, N);
    scatter_ids_kernel<<<dim3((E + 255) / 256), dim3(256), 0, stream>>>(
        eidx, cursor, sorted_e, sorted_nt, E);

    // ---- chunked: MFMA msgs (sorted order) then contiguous segment reduce ----
    for (int lo = 0; lo < E; lo += Ec) {
        int hi = (lo + Ec < E) ? lo + Ec : E;
        int ne = hi - lo;
        edge_mfma_kernel<<<dim3((ne + BM - 1) / BM), dim3(256), 0, stream>>>(
            nodes, edges, sorted_e, sorted_nt, W1h, W1l, W2h, W2l, b1, b2,
            msgs, lo, hi);
        node_reduce_kernel<<<dim3((N + 7) / 8), dim3(256), 0, stream>>>(
            (const float4*)msgs, cursor, (const float4*)nodes, (float4*)out,
            N, lo, hi, lo == 0 ? 1 : 0);
    }
}

// Round 6
// 494.516 us; speedup vs baseline: 8.9651x; 1.0323x over previous
//
#include <hip/hip_runtime.h>
#include <math.h>

#define DD 128   // node / hidden dim
#define FF 64    // edge feature dim
#define BM 64    // edges per tile
#define SENT 0xFFFFFFFFu

typedef __attribute__((ext_vector_type(8))) short bf16x8;
typedef __attribute__((ext_vector_type(4))) short short4s;
typedef __attribute__((ext_vector_type(4))) float f32x4;

__device__ __forceinline__ float ssp_f(float x) {
    float ax = fabsf(x);
    float e  = __expf(-ax);
    return fmaxf(x, 0.0f) + __logf(1.0f + e) - 0.6931471805599453f;
}

__device__ __forceinline__ unsigned short f2bf(float f) {
    unsigned u = __float_as_uint(f);
    unsigned r = (u + 0x7FFFu + ((u >> 16) & 1u)) >> 16;
    return (unsigned short)r;
}
__device__ __forceinline__ float bf2f(unsigned short h) {
    return __uint_as_float(((unsigned)h) << 16);
}

__global__ void copy_nodes_kernel(const float4* __restrict__ src,
                                  float4* __restrict__ dst, int n4) {
    int i = blockIdx.x * blockDim.x + threadIdx.x;
    int stride = gridDim.x * blockDim.x;
    for (; i < n4; i += stride) dst[i] = src[i];
}

__global__ void zero_u32_kernel(unsigned* __restrict__ p, int n) {
    int i = blockIdx.x * blockDim.x + threadIdx.x;
    int stride = gridDim.x * blockDim.x;
    for (; i < n; i += stride) p[i] = 0u;
}

__global__ void hist_kernel(const int* __restrict__ eidx,
                            unsigned* __restrict__ counts, int E) {
    int e = blockIdx.x * blockDim.x + threadIdx.x;
    if (e < E) atomicAdd(&counts[eidx[2 * e]], 1u);
}

__global__ void scan1_kernel(const unsigned* __restrict__ counts,
                             unsigned* __restrict__ cursor,
                             unsigned* __restrict__ bsums, int n) {
    __shared__ unsigned s[256];
    int i = blockIdx.x * 256 + threadIdx.x;
    unsigned v = (i < n) ? counts[i] : 0u;
    s[threadIdx.x] = v;
    __syncthreads();
    #pragma unroll
    for (int d = 1; d < 256; d <<= 1) {
        unsigned t = (threadIdx.x >= d) ? s[threadIdx.x - d] : 0u;
        __syncthreads();
        s[threadIdx.x] += t;
        __syncthreads();
    }
    if (i < n) cursor[i] = s[threadIdx.x] - v;
    if (threadIdx.x == 255) bsums[blockIdx.x] = s[255];
}

__global__ void scan2_kernel(unsigned* __restrict__ bsums, int nb) {
    __shared__ unsigned s[512];
    int t = threadIdx.x;
    if (nb <= 512) {
        unsigned v = (t < nb) ? bsums[t] : 0u;
        s[t] = v;
        __syncthreads();
        #pragma unroll
        for (int d = 1; d < 512; d <<= 1) {
            unsigned x = (t >= d) ? s[t - d] : 0u;
            __syncthreads();
            s[t] += x;
            __syncthreads();
        }
        if (t < nb) bsums[t] = s[t] - v;
    } else if (t == 0) {
        unsigned run = 0u;
        for (int i = 0; i < nb; ++i) { unsigned x = bsums[i]; bsums[i] = run; run += x; }
    }
}

__global__ void scan3_kernel(unsigned* __restrict__ cursor,
                             const unsigned* __restrict__ bsums, int n) {
    int i = blockIdx.x * 256 + threadIdx.x;
    if (i < n) cursor[i] += bsums[blockIdx.x];
}

// after this, cursor[n] == CSR end offset of node n
__global__ void scatter_ids_kernel(const int* __restrict__ eidx,
                                   unsigned* __restrict__ cursor,
                                   unsigned* __restrict__ sorted_e,
                                   unsigned* __restrict__ sorted_nt,
                                   unsigned* __restrict__ sorted_ns, int E) {
    int e = blockIdx.x * blockDim.x + threadIdx.x;
    if (e < E) {
        int ns = eidx[2 * e];
        unsigned pos = atomicAdd(&cursor[ns], 1u);
        sorted_e[pos]  = (unsigned)e;
        sorted_nt[pos] = (unsigned)eidx[2 * e + 1];
        sorted_ns[pos] = (unsigned)ns;
    }
}

// ---- prep: split W[K][128] into bf16 hi/lo, MFMA B-fragment order ----
__global__ void prep_w_kernel(const float* __restrict__ W, int K,
                              unsigned short* __restrict__ hi,
                              unsigned short* __restrict__ lo) {
    int S = K >> 5;
    int idx = blockIdx.x * blockDim.x + threadIdx.x;
    int total = 8 * S * 64;
    if (idx >= total) return;
    int l = idx & 63;
    int s = (idx >> 6) % S;
    int j = idx / (64 * S);
    int col = j * 16 + (l & 15);
    int kbase = s * 32 + (l >> 4) * 8;
    int ob = ((j * S + s) * 64 + l) * 8;
    #pragma unroll
    for (int i = 0; i < 8; ++i) {
        float w = W[(size_t)(kbase + i) * DD + col];
        unsigned short h = f2bf(w);
        hi[ob + i] = h;
        lo[ob + i] = f2bf(w - bf2f(h));
    }
}

// ---- phase 2: fused GEMM1+GEMM2+gather+in-tile segment reduce ----
// smem lifetimes: A(16KB bf16 hi/lo) -> F1(32KB bf16 hi/lo) -> S/M(32KB f32)
__launch_bounds__(256, 2)
__global__ void edge_mfma_kernel(const float* __restrict__ nodes,
                                 const float* __restrict__ edges,
                                 const unsigned* __restrict__ sorted_e,
                                 const unsigned* __restrict__ sorted_nt,
                                 const unsigned* __restrict__ sorted_ns,
                                 const unsigned* __restrict__ ends,
                                 const unsigned short* __restrict__ W1h,
                                 const unsigned short* __restrict__ W1l,
                                 const unsigned short* __restrict__ W2h,
                                 const unsigned short* __restrict__ W2l,
                                 const float* __restrict__ b1,
                                 const float* __restrict__ b2,
                                 float* __restrict__ out,
                                 float* __restrict__ bpart,
                                 unsigned* __restrict__ bnode,
                                 int E) {
    __shared__ unsigned short smem[BM * DD * 2];   // 32 KB, triple-aliased
    __shared__ unsigned ns_l[BM];
    unsigned short* aHi = smem;                    // BM*FF
    unsigned short* aLo = smem + BM * FF;
    unsigned short* fHi = smem;                    // BM*DD (2nd life)
    unsigned short* fLo = smem + BM * DD;
    float* SM = reinterpret_cast<float*>(smem);    // BM*DD f32 (3rd life)

    const int t = threadIdx.x;
    const int tile = blockIdx.x;
    const int tlo = tile * BM;

    if (t < BM) ns_l[t] = (tlo + t < E) ? sorted_ns[tlo + t] : SENT;

    // ---- T14: issue gather of nodes[end] rows into regs NOW; land later ----
    float4 nreg[8];
    #pragma unroll
    for (int it = 0; it < 8; ++it) {
        int idx = it * 256 + t;
        int row = idx >> 5, c4 = idx & 31;
        unsigned nt = (tlo + row < E) ? sorted_nt[tlo + row] : 0u;
        nreg[it] = reinterpret_cast<const float4*>(nodes)[(size_t)nt * 32 + c4];
    }

    // ---- stage edges tile (gathered) fp32 -> bf16 hi/lo, swizzled ----
    const float4* e4 = reinterpret_cast<const float4*>(edges);
    #pragma unroll
    for (int it = 0; it < 4; ++it) {
        int idx = it * 256 + t;
        int row = idx >> 4, c4 = idx & 15;
        int i = tlo + row;
        float4 v = make_float4(0.f, 0.f, 0.f, 0.f);
        if (i < E) {
            unsigned e = sorted_e[i];
            v = e4[(size_t)e * (FF / 4) + c4];
        }
        unsigned short h0 = f2bf(v.x), h1 = f2bf(v.y), h2 = f2bf(v.z), h3 = f2bf(v.w);
        short4s hv = { (short)h0, (short)h1, (short)h2, (short)h3 };
        short4s lv = { (short)f2bf(v.x - bf2f(h0)), (short)f2bf(v.y - bf2f(h1)),
                       (short)f2bf(v.z - bf2f(h2)), (short)f2bf(v.w - bf2f(h3)) };
        int g = c4 >> 1, half = c4 & 1;
        int off = row * FF + ((g ^ (row & 7)) * 8) + half * 4;
        *reinterpret_cast<short4s*>(aHi + off) = hv;
        *reinterpret_cast<short4s*>(aLo + off) = lv;
    }
    __syncthreads();

    const int lane = t & 63, wave = t >> 6;
    const int wrow = wave * 16;
    const int lr = lane & 15, lg = lane >> 4;

    // ---- GEMM1 A-fragments, then A region is dead ----
    bf16x8 a1h[2], a1l[2];
    #pragma unroll
    for (int s = 0; s < 2; ++s) {
        int row = wrow + lr;
        int g = s * 4 + lg;
        int off = row * FF + ((g ^ (row & 7)) * 8);
        a1h[s] = *reinterpret_cast<const bf16x8*>(aHi + off);
        a1l[s] = *reinterpret_cast<const bf16x8*>(aLo + off);
    }
    __syncthreads();

    // ---- GEMM1: [64x64] x [64x128], bf16 split-3 ----
    f32x4 zero4 = { 0.f, 0.f, 0.f, 0.f };
    f32x4 acc1[8];
    #pragma unroll
    for (int j = 0; j < 8; ++j) acc1[j] = zero4;
    #pragma unroll
    for (int j = 0; j < 8; ++j) {
        #pragma unroll
        for (int s = 0; s < 2; ++s) {
            bf16x8 bh = *reinterpret_cast<const bf16x8*>(W1h + ((j * 2 + s) * 64 + lane) * 8);
            bf16x8 bl = *reinterpret_cast<const bf16x8*>(W1l + ((j * 2 + s) * 64 + lane) * 8);
            acc1[j] = __builtin_amdgcn_mfma_f32_16x16x32_bf16(a1h[s], bh, acc1[j], 0, 0, 0);
            acc1[j] = __builtin_amdgcn_mfma_f32_16x16x32_bf16(a1h[s], bl, acc1[j], 0, 0, 0);
            acc1[j] = __builtin_amdgcn_mfma_f32_16x16x32_bf16(a1l[s], bh, acc1[j], 0, 0, 0);
        }
    }

    // ---- epilogue1: bias + ssp + split -> F1 (overlays A) ----
    #pragma unroll
    for (int j = 0; j < 8; ++j) {
        int col = j * 16 + lr;
        float bv = b1[col];
        #pragma unroll
        for (int r = 0; r < 4; ++r) {
            int row = wrow + lg * 4 + r;
            float f = ssp_f(acc1[j][r] + bv);
            unsigned short h = f2bf(f);
            unsigned short l2 = f2bf(f - bf2f(h));
            int off = row * DD + (((col >> 3) ^ (row & 7)) * 8) + (col & 7);
            fHi[off] = h;
            fLo[off] = l2;
        }
    }
    __syncthreads();

    // ---- GEMM2 A-fragments, then F1 region is dead ----
    bf16x8 a2h[4], a2l[4];
    #pragma unroll
    for (int s = 0; s < 4; ++s) {
        int row = wrow + lr;
        int g = s * 4 + lg;
        int off = row * DD + ((g ^ (row & 7)) * 8);
        a2h[s] = *reinterpret_cast<const bf16x8*>(fHi + off);
        a2l[s] = *reinterpret_cast<const bf16x8*>(fLo + off);
    }
    __syncthreads();

    // ---- park gathered node rows into LDS (3rd life), swizzled ----
    #pragma unroll
    for (int it = 0; it < 8; ++it) {
        int idx = it * 256 + t;
        int row = idx >> 5, c4 = idx & 31;
        int off = row * DD + ((c4 * 4) ^ (((row >> 2) & 3) << 4));
        *reinterpret_cast<float4*>(SM + off) = nreg[it];
    }

    // ---- GEMM2: [64x128] x [128x128], bf16 split-3 (no LDS — overlaps) ----
    f32x4 acc2[8];
    #pragma unroll
    for (int j = 0; j < 8; ++j) acc2[j] = zero4;
    #pragma unroll
    for (int j = 0; j < 8; ++j) {
        #pragma unroll
        for (int s = 0; s < 4; ++s) {
            bf16x8 bh = *reinterpret_cast<const bf16x8*>(W2h + ((j * 4 + s) * 64 + lane) * 8);
            bf16x8 bl = *reinterpret_cast<const bf16x8*>(W2l + ((j * 4 + s) * 64 + lane) * 8);
            acc2[j] = __builtin_amdgcn_mfma_f32_16x16x32_bf16(a2h[s], bh, acc2[j], 0, 0, 0);
            acc2[j] = __builtin_amdgcn_mfma_f32_16x16x32_bf16(a2h[s], bl, acc2[j], 0, 0, 0);
            acc2[j] = __builtin_amdgcn_mfma_f32_16x16x32_bf16(a2l[s], bh, acc2[j], 0, 0, 0);
        }
    }
    __syncthreads();   // all S-writes visible

    // ---- epilogue2: msg = ssp(acc2+b2) * node, IN-PLACE in LDS ----
    // each (row,col) slot is read+written by exactly one thread
    #pragma unroll
    for (int j = 0; j < 8; ++j) {
        int col = j * 16 + lr;
        float bv = b2[col];
        #pragma unroll
        for (int r = 0; r < 4; ++r) {
            int row = wrow + lg * 4 + r;
            int off = row * DD + (col ^ (((row >> 2) & 3) << 4));
            float nv = SM[off];
            SM[off] = ssp_f(acc2[j][r] + bv) * nv;
        }
    }
    __syncthreads();

    // ---- in-tile segment reduce over sorted rows (branch is uniform) ----
    if (t < DD) {
        const int col = t;
        unsigned n0 = ns_l[0];
        unsigned s0 = (n0 == 0u) ? 0u : ends[n0 - 1];
        bool contFirst = (s0 < (unsigned)tlo);   // segment continues from prev tile
        if (t == 0) bnode[tile] = contFirst ? n0 : SENT;

        float acc = 0.f;
        unsigned cur = n0;
        int segstart = 0;
        #pragma unroll 1
        for (int r = 0; r < BM; ++r) {
            unsigned n = ns_l[r];
            if (n != cur) {
                if (segstart == 0 && contFirst)
                    bpart[(size_t)tile * DD + col] = acc;
                else
                    out[(size_t)cur * DD + col] = nodes[(size_t)cur * DD + col] + acc;
                cur = n; acc = 0.f; segstart = r;
            }
            acc += SM[r * DD + (col ^ (((r >> 2) & 3) << 4))];
        }
        if (cur != SENT) {
            if (segstart == 0 && contFirst)
                bpart[(size_t)tile * DD + col] = acc;
            else
                out[(size_t)cur * DD + col] = nodes[(size_t)cur * DD + col] + acc;
        }
    }
}

// ---- fixup: add cross-tile boundary partials (runs after edge kernel) ----
__global__ void fixup_bpart_kernel(const float* __restrict__ bpart,
                                   const unsigned* __restrict__ bnode,
                                   float* __restrict__ out, int NT) {
    int ti = blockIdx.x * 2 + (threadIdx.x >> 7);
    if (ti >= NT) return;
    unsigned n = bnode[ti];
    if (n == SENT) return;
    int c = threadIdx.x & 127;
    atomicAdd(&out[(size_t)n * DD + c], bpart[(size_t)ti * DD + c]);
}

// ---- nodes with zero out-edges: out = nodes ----
__global__ void copy_empty_kernel(const unsigned* __restrict__ counts,
                                  const float4* __restrict__ nodes4,
                                  float4* __restrict__ out4, int N) {
    int n = blockIdx.x * 8 + (threadIdx.x >> 5);
    if (n >= N) return;
    if (counts[n] != 0u) return;
    int d4 = threadIdx.x & 31;
    out4[(size_t)n * 32 + d4] = nodes4[(size_t)n * 32 + d4];
}

// ---- fallback: fused atomic kernel (used only if ws too small) ----
__launch_bounds__(256, 2)
__global__ void edge_fused_atomic_kernel(const float* __restrict__ nodes,
                                         const float* __restrict__ edges,
                                         const int*   __restrict__ eidx,
                                         const float* __restrict__ W1,
                                         const float* __restrict__ b1,
                                         const float* __restrict__ W2,
                                         const float* __restrict__ b2,
                                         float* __restrict__ out, int E) {
    int e = blockIdx.x * 256 + threadIdx.x;
    if (e >= E) return;
    int ns = eidx[2 * e + 0];
    int nt = eidx[2 * e + 1];

    float h1[DD];
    #pragma unroll
    for (int d = 0; d < DD; ++d) h1[d] = b1[d];
    const float4* ev4 = reinterpret_cast<const float4*>(edges) + (size_t)e * (FF / 4);
    #pragma unroll 1
    for (int f4 = 0; f4 < FF / 4; ++f4) {
        float4 ev = ev4[f4];
        const float* w0 = W1 + (size_t)(f4 * 4) * DD;
        #pragma unroll
        for (int d = 0; d < DD; ++d) h1[d] = fmaf(ev.x, w0[d], h1[d]);
        #pragma unroll
        for (int d = 0; d < DD; ++d) h1[d] = fmaf(ev.y, w0[DD + d], h1[d]);
        #pragma unroll
        for (int d = 0; d < DD; ++d) h1[d] = fmaf(ev.z, w0[2 * DD + d], h1[d]);
        #pragma unroll
        for (int d = 0; d < DD; ++d) h1[d] = fmaf(ev.w, w0[3 * DD + d], h1[d]);
    }
    #pragma unroll
    for (int d = 0; d < DD; ++d) h1[d] = ssp_f(h1[d]);

    const float* nrow = nodes + (size_t)nt * DD;
    float*       orow = out   + (size_t)ns * DD;
    #pragma unroll 1
    for (int c = 0; c < 2; ++c) {
        const int base = c * 64;
        float h2[64];
        #pragma unroll
        for (int j = 0; j < 64; ++j) h2[j] = b2[base + j];
        #pragma unroll
        for (int k = 0; k < DD; ++k) {
            float hk = h1[k];
            const float* w = W2 + (size_t)k * DD + base;
            #pragma unroll
            for (int j = 0; j < 64; ++j) h2[j] = fmaf(hk, w[j], h2[j]);
        }
        #pragma unroll
        for (int j = 0; j < 64; ++j) {
            float m = ssp_f(h2[j]) * nrow[base + j];
            __hip_atomic_fetch_add(&orow[base + j], m,
                                   __ATOMIC_RELAXED, __HIP_MEMORY_SCOPE_AGENT);
        }
    }
}

extern "C" void kernel_launch(void* const* d_in, const int* in_sizes, int n_in,
                              void* d_out, int out_size, void* d_ws, size_t ws_size,
                              hipStream_t stream) {
    const float* nodes = (const float*)d_in[0];
    const float* edges = (const float*)d_in[1];
    const int*   eidx  = (const int*)  d_in[2];
    const float* W1    = (const float*)d_in[3];
    const float* b1    = (const float*)d_in[4];
    const float* W2    = (const float*)d_in[5];
    const float* b2    = (const float*)d_in[6];
    float* out = (float*)d_out;

    int ND = in_sizes[0];        // N*D
    int N  = ND / DD;            // 100000
    int E  = in_sizes[1] / FF;   // 600000
    int NT = (E + BM - 1) / BM;  // tiles

    // ---- workspace layout ----
    int nb = (N + 255) / 256;
    uintptr_t base = (uintptr_t)d_ws;
    uintptr_t p = base;
    unsigned* counts    = (unsigned*)p;  p += (size_t)N * 4;
    unsigned* cursor    = (unsigned*)p;  p += (size_t)N * 4;
    unsigned* bsums     = (unsigned*)p;  p += (size_t)nb * 4;
    unsigned* sorted_e  = (unsigned*)p;  p += (size_t)E * 4;
    unsigned* sorted_nt = (unsigned*)p;  p += (size_t)E * 4;
    unsigned* sorted_ns = (unsigned*)p;  p += (size_t)E * 4;
    p = (p + 255) & ~(uintptr_t)255;
    unsigned short* W1h = (unsigned short*)p;  p += (size_t)FF * DD * 2;
    unsigned short* W1l = (unsigned short*)p;  p += (size_t)FF * DD * 2;
    unsigned short* W2h = (unsigned short*)p;  p += (size_t)DD * DD * 2;
    unsigned short* W2l = (unsigned short*)p;  p += (size_t)DD * DD * 2;
    unsigned* bnode     = (unsigned*)p;  p += (size_t)NT * 4;
    p = (p + 255) & ~(uintptr_t)255;
    float* bpart        = (float*)p;     p += (size_t)NT * DD * 4;

    if ((size_t)(p - base) > ws_size) {
        copy_nodes_kernel<<<dim3(1024), dim3(256), 0, stream>>>(
            (const float4*)nodes, (float4*)out, ND / 4);
        edge_fused_atomic_kernel<<<dim3((E + 255) / 256), dim3(256), 0, stream>>>(
            nodes, edges, eidx, W1, b1, W2, b2, out, E);
        return;
    }

    // ---- prep weight fragments (bf16 split, MFMA B layout) ----
    prep_w_kernel<<<dim3(4), dim3(256), 0, stream>>>(W1, FF, W1h, W1l);
    prep_w_kernel<<<dim3(8), dim3(256), 0, stream>>>(W2, DD, W2h, W2l);

    // ---- counting sort by start node -> sorted arrays + CSR end offsets ----
    zero_u32_kernel<<<dim3(256), dim3(256), 0, stream>>>(counts, N);
    hist_kernel<<<dim3((E + 255) / 256), dim3(256), 0, stream>>>(eidx, counts, E);
    scan1_kernel<<<dim3(nb), dim3(256), 0, stream>>>(counts, cursor, bsums, N);
    scan2_kernel<<<dim3(1), dim3(512), 0, stream>>>(bsums, nb);
    scan3_kernel<<<dim3(nb), dim3(256), 0, stream>>>(cursor, bsums, N);
    scatter_ids_kernel<<<dim3((E + 255) / 256), dim3(256), 0, stream>>>(
        eidx, cursor, sorted_e, sorted_nt, sorted_ns, E);

    // ---- zero-edge nodes: out = nodes (independent of edge kernel) ----
    copy_empty_kernel<<<dim3((N + 7) / 8), dim3(256), 0, stream>>>(
        counts, (const float4*)nodes, (float4*)out, N);

    // ---- fused edge kernel with in-tile segment reduce ----
    edge_mfma_kernel<<<dim3(NT), dim3(256), 0, stream>>>(
        nodes, edges, sorted_e, sorted_nt, sorted_ns, cursor,
        W1h, W1l, W2h, W2l, b1, b2, out, bpart, bnode, E);

    // ---- cross-tile boundary fixup ----
    fixup_bpart_kernel<<<dim3((NT + 1) / 2), dim3(256), 0, stream>>>(
        bpart, bnode, out, NT);
}

// Round 7
// 448.470 us; speedup vs baseline: 9.8855x; 1.1027x over previous
//
#include <hip/hip_runtime.h>
#include <math.h>

#define DD 128   // node / hidden dim
#define FF 64    // edge feature dim
#define BM 64    // edges per tile
#define SENT 0xFFFFFFFFu

typedef __attribute__((ext_vector_type(8))) short bf16x8;
typedef __attribute__((ext_vector_type(4))) short short4s;
typedef __attribute__((ext_vector_type(4))) float f32x4;

__device__ __forceinline__ float ssp_f(float x) {
    float ax = fabsf(x);
    float e  = __expf(-ax);
    return fmaxf(x, 0.0f) + __logf(1.0f + e) - 0.6931471805599453f;
}

__device__ __forceinline__ unsigned short f2bf(float f) {
    unsigned u = __float_as_uint(f);
    unsigned r = (u + 0x7FFFu + ((u >> 16) & 1u)) >> 16;
    return (unsigned short)r;
}
__device__ __forceinline__ float bf2f(unsigned short h) {
    return __uint_as_float(((unsigned)h) << 16);
}

__global__ void copy_nodes_kernel(const float4* __restrict__ src,
                                  float4* __restrict__ dst, int n4) {
    int i = blockIdx.x * blockDim.x + threadIdx.x;
    int stride = gridDim.x * blockDim.x;
    for (; i < n4; i += stride) dst[i] = src[i];
}

__global__ void zero_u32_kernel(unsigned* __restrict__ p, int n) {
    int i = blockIdx.x * blockDim.x + threadIdx.x;
    int stride = gridDim.x * blockDim.x;
    for (; i < n; i += stride) p[i] = 0u;
}

__global__ void hist_kernel(const int* __restrict__ eidx,
                            unsigned* __restrict__ counts, int E) {
    int e = blockIdx.x * blockDim.x + threadIdx.x;
    if (e < E) atomicAdd(&counts[eidx[2 * e]], 1u);
}

__global__ void scan1_kernel(const unsigned* __restrict__ counts,
                             unsigned* __restrict__ cursor,
                             unsigned* __restrict__ bsums, int n) {
    __shared__ unsigned s[256];
    int i = blockIdx.x * 256 + threadIdx.x;
    unsigned v = (i < n) ? counts[i] : 0u;
    s[threadIdx.x] = v;
    __syncthreads();
    #pragma unroll
    for (int d = 1; d < 256; d <<= 1) {
        unsigned t = (threadIdx.x >= d) ? s[threadIdx.x - d] : 0u;
        __syncthreads();
        s[threadIdx.x] += t;
        __syncthreads();
    }
    if (i < n) cursor[i] = s[threadIdx.x] - v;
    if (threadIdx.x == 255) bsums[blockIdx.x] = s[255];
}

__global__ void scan2_kernel(unsigned* __restrict__ bsums, int nb) {
    __shared__ unsigned s[512];
    int t = threadIdx.x;
    if (nb <= 512) {
        unsigned v = (t < nb) ? bsums[t] : 0u;
        s[t] = v;
        __syncthreads();
        #pragma unroll
        for (int d = 1; d < 512; d <<= 1) {
            unsigned x = (t >= d) ? s[t - d] : 0u;
            __syncthreads();
            s[t] += x;
            __syncthreads();
        }
        if (t < nb) bsums[t] = s[t] - v;
    } else if (t == 0) {
        unsigned run = 0u;
        for (int i = 0; i < nb; ++i) { unsigned x = bsums[i]; bsums[i] = run; run += x; }
    }
}

__global__ void scan3_kernel(unsigned* __restrict__ cursor,
                             const unsigned* __restrict__ bsums, int n) {
    int i = blockIdx.x * 256 + threadIdx.x;
    if (i < n) cursor[i] += bsums[blockIdx.x];
}

// after this, cursor[n] == CSR end offset of node n
__global__ void scatter_ids_kernel(const int* __restrict__ eidx,
                                   unsigned* __restrict__ cursor,
                                   unsigned* __restrict__ sorted_e,
                                   unsigned* __restrict__ sorted_nt,
                                   unsigned* __restrict__ sorted_ns, int E) {
    int e = blockIdx.x * blockDim.x + threadIdx.x;
    if (e < E) {
        int ns = eidx[2 * e];
        unsigned pos = atomicAdd(&cursor[ns], 1u);
        sorted_e[pos]  = (unsigned)e;
        sorted_nt[pos] = (unsigned)eidx[2 * e + 1];
        sorted_ns[pos] = (unsigned)ns;
    }
}

// ---- prep: split W[K][128] into bf16 hi/lo, MFMA B-fragment order ----
__global__ void prep_w_kernel(const float* __restrict__ W, int K,
                              unsigned short* __restrict__ hi,
                              unsigned short* __restrict__ lo) {
    int S = K >> 5;
    int idx = blockIdx.x * blockDim.x + threadIdx.x;
    int total = 8 * S * 64;
    if (idx >= total) return;
    int l = idx & 63;
    int s = (idx >> 6) % S;
    int j = idx / (64 * S);
    int col = j * 16 + (l & 15);
    int kbase = s * 32 + (l >> 4) * 8;
    int ob = ((j * S + s) * 64 + l) * 8;
    #pragma unroll
    for (int i = 0; i < 8; ++i) {
        float w = W[(size_t)(kbase + i) * DD + col];
        unsigned short h = f2bf(w);
        hi[ob + i] = h;
        lo[ob + i] = f2bf(w - bf2f(h));
    }
}

// ---- phase 2: fused GEMM1+GEMM2+gather-multiply+in-tile segment reduce ----
// smem lifetimes: A(16KB bf16 hi/lo) -> F1(32KB bf16 hi/lo) -> S/M(32KB f32)
__launch_bounds__(256, 4)
__global__ void edge_mfma_kernel(const float* __restrict__ nodes,
                                 const float* __restrict__ edges,
                                 const unsigned* __restrict__ sorted_e,
                                 const unsigned* __restrict__ sorted_nt,
                                 const unsigned* __restrict__ sorted_ns,
                                 const unsigned* __restrict__ ends,
                                 const unsigned short* __restrict__ W1h,
                                 const unsigned short* __restrict__ W1l,
                                 const unsigned short* __restrict__ W2h,
                                 const unsigned short* __restrict__ W2l,
                                 const float* __restrict__ b1,
                                 const float* __restrict__ b2,
                                 float* __restrict__ out,
                                 float* __restrict__ bpart,
                                 unsigned* __restrict__ bnode,
                                 int E) {
    __shared__ unsigned short smem[BM * DD * 2];   // 32768 B exactly, aliased
    unsigned short* aHi = smem;                    // BM*FF
    unsigned short* aLo = smem + BM * FF;
    unsigned short* fHi = smem;                    // BM*DD (2nd life)
    unsigned short* fLo = smem + BM * DD;
    float* SM = reinterpret_cast<float*>(smem);    // BM*DD f32 (3rd life)

    const int t = threadIdx.x;
    const int tile = blockIdx.x;
    const int tlo = tile * BM;

    // per-lane copy of this tile's start-node ids (for the reduce broadcast)
    unsigned ns_reg = (tlo + (t & 63) < E) ? sorted_ns[tlo + (t & 63)] : SENT;

    // ---- stage edges tile (gathered) fp32 -> bf16 hi/lo, swizzled ----
    const float4* e4 = reinterpret_cast<const float4*>(edges);
    #pragma unroll
    for (int it = 0; it < 4; ++it) {
        int idx = it * 256 + t;
        int row = idx >> 4, c4 = idx & 15;
        int i = tlo + row;
        float4 v = make_float4(0.f, 0.f, 0.f, 0.f);
        if (i < E) {
            unsigned e = sorted_e[i];
            v = e4[(size_t)e * (FF / 4) + c4];
        }
        unsigned short h0 = f2bf(v.x), h1 = f2bf(v.y), h2 = f2bf(v.z), h3 = f2bf(v.w);
        short4s hv = { (short)h0, (short)h1, (short)h2, (short)h3 };
        short4s lv = { (short)f2bf(v.x - bf2f(h0)), (short)f2bf(v.y - bf2f(h1)),
                       (short)f2bf(v.z - bf2f(h2)), (short)f2bf(v.w - bf2f(h3)) };
        int g = c4 >> 1, half = c4 & 1;
        int off = row * FF + ((g ^ (row & 7)) * 8) + half * 4;
        *reinterpret_cast<short4s*>(aHi + off) = hv;
        *reinterpret_cast<short4s*>(aLo + off) = lv;
    }
    __syncthreads();

    const int lane = t & 63, wave = t >> 6;
    const int wrow = wave * 16;
    const int lr = lane & 15, lg = lane >> 4;

    // ---- GEMM1 A-fragments, then A region is dead ----
    bf16x8 a1h[2], a1l[2];
    #pragma unroll
    for (int s = 0; s < 2; ++s) {
        int row = wrow + lr;
        int g = s * 4 + lg;
        int off = row * FF + ((g ^ (row & 7)) * 8);
        a1h[s] = *reinterpret_cast<const bf16x8*>(aHi + off);
        a1l[s] = *reinterpret_cast<const bf16x8*>(aLo + off);
    }
    __syncthreads();

    // ---- GEMM1: [64x64] x [64x128], bf16 split-3; W loads grouped per j ----
    f32x4 zero4 = { 0.f, 0.f, 0.f, 0.f };
    f32x4 acc1[8];
    #pragma unroll
    for (int j = 0; j < 8; ++j) acc1[j] = zero4;
    #pragma unroll
    for (int j = 0; j < 8; ++j) {
        bf16x8 bh[2], bl[2];
        #pragma unroll
        for (int s = 0; s < 2; ++s) {
            bh[s] = *reinterpret_cast<const bf16x8*>(W1h + ((size_t)((j * 2 + s) * 64 + lane)) * 8);
            bl[s] = *reinterpret_cast<const bf16x8*>(W1l + ((size_t)((j * 2 + s) * 64 + lane)) * 8);
        }
        #pragma unroll
        for (int s = 0; s < 2; ++s) {
            acc1[j] = __builtin_amdgcn_mfma_f32_16x16x32_bf16(a1h[s], bh[s], acc1[j], 0, 0, 0);
            acc1[j] = __builtin_amdgcn_mfma_f32_16x16x32_bf16(a1h[s], bl[s], acc1[j], 0, 0, 0);
            acc1[j] = __builtin_amdgcn_mfma_f32_16x16x32_bf16(a1l[s], bh[s], acc1[j], 0, 0, 0);
        }
    }

    // ---- epilogue1: bias + ssp + split -> F1 (overlays A) ----
    #pragma unroll
    for (int j = 0; j < 8; ++j) {
        int col = j * 16 + lr;
        float bv = b1[col];
        #pragma unroll
        for (int r = 0; r < 4; ++r) {
            int row = wrow + lg * 4 + r;
            float f = ssp_f(acc1[j][r] + bv);
            unsigned short h = f2bf(f);
            unsigned short l2 = f2bf(f - bf2f(h));
            int off = row * DD + (((col >> 3) ^ (row & 7)) * 8) + (col & 7);
            fHi[off] = h;
            fLo[off] = l2;
        }
    }
    __syncthreads();

    // ---- GEMM2 A-fragments, then F1 region is dead ----
    bf16x8 a2h[4], a2l[4];
    #pragma unroll
    for (int s = 0; s < 4; ++s) {
        int row = wrow + lr;
        int g = s * 4 + lg;
        int off = row * DD + ((g ^ (row & 7)) * 8);
        a2h[s] = *reinterpret_cast<const bf16x8*>(fHi + off);
        a2l[s] = *reinterpret_cast<const bf16x8*>(fLo + off);
    }
    __syncthreads();

    // ---- GEMM2: [64x128] x [128x128], bf16 split-3; W loads grouped per j ----
    f32x4 acc2[8];
    #pragma unroll
    for (int j = 0; j < 8; ++j) acc2[j] = zero4;
    #pragma unroll
    for (int j = 0; j < 8; ++j) {
        bf16x8 bh[4], bl[4];
        #pragma unroll
        for (int s = 0; s < 4; ++s) {
            bh[s] = *reinterpret_cast<const bf16x8*>(W2h + ((size_t)((j * 4 + s) * 64 + lane)) * 8);
            bl[s] = *reinterpret_cast<const bf16x8*>(W2l + ((size_t)((j * 4 + s) * 64 + lane)) * 8);
        }
        #pragma unroll
        for (int s = 0; s < 4; ++s) {
            acc2[j] = __builtin_amdgcn_mfma_f32_16x16x32_bf16(a2h[s], bh[s], acc2[j], 0, 0, 0);
            acc2[j] = __builtin_amdgcn_mfma_f32_16x16x32_bf16(a2h[s], bl[s], acc2[j], 0, 0, 0);
            acc2[j] = __builtin_amdgcn_mfma_f32_16x16x32_bf16(a2l[s], bh[s], acc2[j], 0, 0, 0);
        }
    }

    // ---- epilogue2: filt = ssp(acc2 + b2) -> SM (f32, swizzled) ----
    // (SM aliases F1; the barrier above guarantees all a2 reads are done)
    #pragma unroll
    for (int j = 0; j < 8; ++j) {
        int col = j * 16 + lr;
        float bv = b2[col];
        #pragma unroll
        for (int r = 0; r < 4; ++r) {
            int row = wrow + lg * 4 + r;
            SM[row * DD + (col ^ ((row & 7) << 2))] = ssp_f(acc2[j][r] + bv);
        }
    }
    __syncthreads();

    // ---- multiply: SM[row] *= nodes[nt[row]], float4 coalesced ----
    #pragma unroll
    for (int it = 0; it < 8; ++it) {
        int idx = it * 256 + t;
        int row = idx >> 5, c4 = idx & 31;
        unsigned nt = (tlo + row < E) ? sorted_nt[tlo + row] : 0u;
        float4 nv = reinterpret_cast<const float4*>(nodes)[(size_t)nt * 32 + c4];
        int foff = row * DD + ((c4 * 4) ^ ((row & 7) << 2));
        float4 mv = *reinterpret_cast<float4*>(SM + foff);
        mv.x *= nv.x; mv.y *= nv.y; mv.z *= nv.z; mv.w *= nv.w;
        *reinterpret_cast<float4*>(SM + foff) = mv;
    }
    __syncthreads();

    // ---- in-tile segment reduce over sorted rows (uniform branch) ----
    if (t < DD) {
        const int col = t;
        unsigned n0 = __shfl(ns_reg, 0);
        unsigned s0 = (n0 == 0u) ? 0u : ends[n0 - 1];
        bool contFirst = (s0 < (unsigned)tlo);   // segment continues from prev tile
        if (t == 0) bnode[tile] = contFirst ? n0 : SENT;

        float acc = 0.f;
        unsigned cur = n0;
        int segstart = 0;
        #pragma unroll 1
        for (int r = 0; r < BM; ++r) {
            unsigned n = __shfl(ns_reg, r);
            if (n != cur) {
                if (segstart == 0 && contFirst)
                    bpart[(size_t)tile * DD + col] = acc;
                else
                    out[(size_t)cur * DD + col] = nodes[(size_t)cur * DD + col] + acc;
                cur = n; acc = 0.f; segstart = r;
            }
            acc += SM[r * DD + (col ^ ((r & 7) << 2))];
        }
        if (cur != SENT) {
            if (segstart == 0 && contFirst)
                bpart[(size_t)tile * DD + col] = acc;
            else
                out[(size_t)cur * DD + col] = nodes[(size_t)cur * DD + col] + acc;
        }
    }
}

// ---- fixup: add cross-tile boundary partials (runs after edge kernel) ----
__global__ void fixup_bpart_kernel(const float* __restrict__ bpart,
                                   const unsigned* __restrict__ bnode,
                                   float* __restrict__ out, int NT) {
    int ti = blockIdx.x * 2 + (threadIdx.x >> 7);
    if (ti >= NT) return;
    unsigned n = bnode[ti];
    if (n == SENT) return;
    int c = threadIdx.x & 127;
    atomicAdd(&out[(size_t)n * DD + c], bpart[(size_t)ti * DD + c]);
}

// ---- nodes with zero out-edges: out = nodes ----
__global__ void copy_empty_kernel(const unsigned* __restrict__ counts,
                                  const float4* __restrict__ nodes4,
                                  float4* __restrict__ out4, int N) {
    int n = blockIdx.x * 8 + (threadIdx.x >> 5);
    if (n >= N) return;
    if (counts[n] != 0u) return;
    int d4 = threadIdx.x & 31;
    out4[(size_t)n * 32 + d4] = nodes4[(size_t)n * 32 + d4];
}

// ---- fallback: fused atomic kernel (used only if ws too small) ----
__launch_bounds__(256, 2)
__global__ void edge_fused_atomic_kernel(const float* __restrict__ nodes,
                                         const float* __restrict__ edges,
                                         const int*   __restrict__ eidx,
                                         const float* __restrict__ W1,
                                         const float* __restrict__ b1,
                                         const float* __restrict__ W2,
                                         const float* __restrict__ b2,
                                         float* __restrict__ out, int E) {
    int e = blockIdx.x * 256 + threadIdx.x;
    if (e >= E) return;
    int ns = eidx[2 * e + 0];
    int nt = eidx[2 * e + 1];

    float h1[DD];
    #pragma unroll
    for (int d = 0; d < DD; ++d) h1[d] = b1[d];
    const float4* ev4 = reinterpret_cast<const float4*>(edges) + (size_t)e * (FF / 4);
    #pragma unroll 1
    for (int f4 = 0; f4 < FF / 4; ++f4) {
        float4 ev = ev4[f4];
        const float* w0 = W1 + (size_t)(f4 * 4) * DD;
        #pragma unroll
        for (int d = 0; d < DD; ++d) h1[d] = fmaf(ev.x, w0[d], h1[d]);
        #pragma unroll
        for (int d = 0; d < DD; ++d) h1[d] = fmaf(ev.y, w0[DD + d], h1[d]);
        #pragma unroll
        for (int d = 0; d < DD; ++d) h1[d] = fmaf(ev.z, w0[2 * DD + d], h1[d]);
        #pragma unroll
        for (int d = 0; d < DD; ++d) h1[d] = fmaf(ev.w, w0[3 * DD + d], h1[d]);
    }
    #pragma unroll
    for (int d = 0; d < DD; ++d) h1[d] = ssp_f(h1[d]);

    const float* nrow = nodes + (size_t)nt * DD;
    float*       orow = out   + (size_t)ns * DD;
    #pragma unroll 1
    for (int c = 0; c < 2; ++c) {
        const int base = c * 64;
        float h2[64];
        #pragma unroll
        for (int j = 0; j < 64; ++j) h2[j] = b2[base + j];
        #pragma unroll
        for (int k = 0; k < DD; ++k) {
            float hk = h1[k];
            const float* w = W2 + (size_t)k * DD + base;
            #pragma unroll
            for (int j = 0; j < 64; ++j) h2[j] = fmaf(hk, w[j], h2[j]);
        }
        #pragma unroll
        for (int j = 0; j < 64; ++j) {
            float m = ssp_f(h2[j]) * nrow[base + j];
            __hip_atomic_fetch_add(&orow[base + j], m,
                                   __ATOMIC_RELAXED, __HIP_MEMORY_SCOPE_AGENT);
        }
    }
}

extern "C" void kernel_launch(void* const* d_in, const int* in_sizes, int n_in,
                              void* d_out, int out_size, void* d_ws, size_t ws_size,
                              hipStream_t stream) {
    const float* nodes = (const float*)d_in[0];
    const float* edges = (const float*)d_in[1];
    const int*   eidx  = (const int*)  d_in[2];
    const float* W1    = (const float*)d_in[3];
    const float* b1    = (const float*)d_in[4];
    const float* W2    = (const float*)d_in[5];
    const float* b2    = (const float*)d_in[6];
    float* out = (float*)d_out;

    int ND = in_sizes[0];        // N*D
    int N  = ND / DD;            // 100000
    int E  = in_sizes[1] / FF;   // 600000
    int NT = (E + BM - 1) / BM;  // tiles

    // ---- workspace layout ----
    int nb = (N + 255) / 256;
    uintptr_t base = (uintptr_t)d_ws;
    uintptr_t p = base;
    unsigned* counts    = (unsigned*)p;  p += (size_t)N * 4;
    unsigned* cursor    = (unsigned*)p;  p += (size_t)N * 4;
    unsigned* bsums     = (unsigned*)p;  p += (size_t)nb * 4;
    unsigned* sorted_e  = (unsigned*)p;  p += (size_t)E * 4;
    unsigned* sorted_nt = (unsigned*)p;  p += (size_t)E * 4;
    unsigned* sorted_ns = (unsigned*)p;  p += (size_t)E * 4;
    p = (p + 255) & ~(uintptr_t)255;
    unsigned short* W1h = (unsigned short*)p;  p += (size_t)FF * DD * 2;
    unsigned short* W1l = (unsigned short*)p;  p += (size_t)FF * DD * 2;
    unsigned short* W2h = (unsigned short*)p;  p += (size_t)DD * DD * 2;
    unsigned short* W2l = (unsigned short*)p;  p += (size_t)DD * DD * 2;
    unsigned* bnode     = (unsigned*)p;  p += (size_t)NT * 4;
    p = (p + 255) & ~(uintptr_t)255;
    float* bpart        = (float*)p;     p += (size_t)NT * DD * 4;

    if ((size_t)(p - base) > ws_size) {
        copy_nodes_kernel<<<dim3(1024), dim3(256), 0, stream>>>(
            (const float4*)nodes, (float4*)out, ND / 4);
        edge_fused_atomic_kernel<<<dim3((E + 255) / 256), dim3(256), 0, stream>>>(
            nodes, edges, eidx, W1, b1, W2, b2, out, E);
        return;
    }

    // ---- prep weight fragments (bf16 split, MFMA B layout) ----
    prep_w_kernel<<<dim3(4), dim3(256), 0, stream>>>(W1, FF, W1h, W1l);
    prep_w_kernel<<<dim3(8), dim3(256), 0, stream>>>(W2, DD, W2h, W2l);

    // ---- counting sort by start node -> sorted arrays + CSR end offsets ----
    zero_u32_kernel<<<dim3(256), dim3(256), 0, stream>>>(counts, N);
    hist_kernel<<<dim3((E + 255) / 256), dim3(256), 0, stream>>>(eidx, counts, E);
    scan1_kernel<<<dim3(nb), dim3(256), 0, stream>>>(counts, cursor, bsums, N);
    scan2_kernel<<<dim3(1), dim3(512), 0, stream>>>(bsums, nb);
    scan3_kernel<<<dim3(nb), dim3(256), 0, stream>>>(cursor, bsums, N);
    scatter_ids_kernel<<<dim3((E + 255) / 256), dim3(256), 0, stream>>>(
        eidx, cursor, sorted_e, sorted_nt, sorted_ns, E);

    // ---- zero-edge nodes: out = nodes (independent of edge kernel) ----
    copy_empty_kernel<<<dim3((N + 7) / 8), dim3(256), 0, stream>>>(
        counts, (const float4*)nodes, (float4*)out, N);

    // ---- fused edge kernel with in-tile segment reduce ----
    edge_mfma_kernel<<<dim3(NT), dim3(256), 0, stream>>>(
        nodes, edges, sorted_e, sorted_nt, sorted_ns, cursor,
        W1h, W1l, W2h, W2l, b1, b2, out, bpart, bnode, E);

    // ---- cross-tile boundary fixup ----
    fixup_bpart_kernel<<<dim3((NT + 1) / 2), dim3(256), 0, stream>>>(
        bpart, bnode, out, NT);
}